// Round 11
// baseline (432.419 us; speedup 1.0000x reference)
//
#include <hip/hip_runtime.h>
#include <hip/hip_bf16.h>
#include <stdint.h>

typedef __hip_bfloat16 bf16;
typedef __attribute__((ext_vector_type(8))) short short8;
typedef __attribute__((ext_vector_type(4))) float floatx4;

#define D_MODEL 1024
#define D_STATE 16
#define D_INNER 2048
#define DT_RANK 64
#define BB 2
#define LL 2048
#define BL (BB * LL)            // 4096 rows
#define XZ_LD (2 * D_INNER)     // 4096 (fallback path only)
#define DBL_LD (DT_RANK + 2 * D_STATE)  // 96
#define NCH 32                  // time chunks for parallel scan
#define TCH (LL / NCH)          // 64 steps per chunk

__device__ __forceinline__ bf16 f2b(float f) { return __float2bfloat16(f); }

// fast sigmoid / softplus via native v_exp/v_log/v_rcp (~3e-7 rel err)
__device__ __forceinline__ float fsig(float v)  { return __fdividef(1.f, 1.f + __expf(-v)); }
__device__ __forceinline__ float fsoftp(float v){ return fmaxf(v, 0.f) + __logf(1.f + __expf(-fabsf(v))); }

// async 16B global -> LDS (wave-uniform LDS base + lane*16; rows contiguous)
__device__ __forceinline__ void gload16(const void* g, void* l) {
    __builtin_amdgcn_global_load_lds(
        (const __attribute__((address_space(1))) uint32_t*)(uintptr_t)g,
        (__attribute__((address_space(3))) uint32_t*)(uintptr_t)l,
        16, 0, 0);
}

// ---------------- LayerNorm: one block per row; bf16 and/or fp32 out ---------
__global__ __launch_bounds__(256) void ln_kernel(
    const float* __restrict__ x, const float* __restrict__ w,
    const float* __restrict__ b, float* __restrict__ xnf, bf16* __restrict__ xnb)
{
    __shared__ float s1[256], s2[256];
    const int row = blockIdx.x;
    const int tid = threadIdx.x;
    const float* xr = x + (size_t)row * D_MODEL;
    float v[4], sum = 0.f, sq = 0.f;
#pragma unroll
    for (int i = 0; i < 4; ++i) {
        v[i] = xr[tid + 256 * i];
        sum += v[i];
        sq  += v[i] * v[i];
    }
    s1[tid] = sum; s2[tid] = sq;
    __syncthreads();
    for (int s = 128; s > 0; s >>= 1) {
        if (tid < s) { s1[tid] += s1[tid + s]; s2[tid] += s2[tid + s]; }
        __syncthreads();
    }
    const float mu  = s1[0] * (1.f / D_MODEL);
    const float var = s2[0] * (1.f / D_MODEL) - mu * mu;
    const float rs  = rsqrtf(var + 1e-5f);
#pragma unroll
    for (int i = 0; i < 4; ++i) {
        const int c = tid + 256 * i;
        const float r = (v[i] - mu) * rs * w[c] + b[c];
        if (xnb) xnb[(size_t)row * D_MODEL + c] = f2b(r);
        if (xnf) xnf[(size_t)row * D_MODEL + c] = r;
    }
}

// ------------- out pre-init with residual x (for G7 split-K atomics) ---------
// launched FIRST so its dirty L2 lines drain during wcvt+ln, not during G2.
__global__ __launch_bounds__(256) void init_out(
    const float* __restrict__ x, float* __restrict__ out)
{
    const int id = blockIdx.x * 256 + threadIdx.x;
    ((float4*)out)[id] = ((const float4*)x)[id];
}

// --------- fused fp32->bf16 weight conversion (+pad W_xproj, +zero dbl) ------
#define S0 (4096 * 1024)   // W_in
#define S1 (128 * 2048)    // W_xproj padded to 128 rows
#define S2 (2048 * 64)     // W_dt
#define S3 (1024 * 2048)   // W_out
#define S4 (BL * DBL_LD)   // dbl zero-init (for split-K atomics)

__global__ __launch_bounds__(256) void wcvt_kernel(
    const float* __restrict__ Win, const float* __restrict__ Wx,
    const float* __restrict__ Wdt, const float* __restrict__ Wout,
    bf16* __restrict__ win_bf, bf16* __restrict__ wx_bf,
    bf16* __restrict__ wdt_bf, bf16* __restrict__ wout_bf,
    float* __restrict__ dbl)
{
    int id = blockIdx.x * 256 + threadIdx.x;
    if (id < S0) { win_bf[id] = f2b(Win[id]); return; }
    id -= S0;
    if (id < S1) { wx_bf[id] = (id < 96 * 2048) ? f2b(Wx[id]) : f2b(0.f); return; }
    id -= S1;
    if (id < S2) { wdt_bf[id] = f2b(Wdt[id]); return; }
    id -= S2;
    if (id < S3) { wout_bf[id] = f2b(Wout[id]); return; }
    id -= S3;
    dbl[id] = 0.f;
}

// ============ bf16 MFMA GEMM (R9-proven, BK=32): C = A[M,K] * B[N,K]^T =======
// epi: 1=+bias softplus; 2=+resid; 3=atomicAdd (split-K, K=slice len);
//      4=u/z split (gn<D_INNER -> fp32 C, else bf16 C2)
#define GTM 128
#define GTN 128
#define GTK 32

__global__ __launch_bounds__(256) void gemm_bf(
    const bf16* __restrict__ A, int lda,
    const bf16* __restrict__ B, int ldb,
    float* __restrict__ C, int ldc,
    int N, int K, int epi,
    const float* __restrict__ bias,
    const float* __restrict__ resid,
    bf16* __restrict__ C2)
{
    __shared__ short As[GTM * GTK];   // 8 KB
    __shared__ short Bs[GTN * GTK];   // 8 KB
    const int tid  = threadIdx.x;
    const int lane = tid & 63;
    const int wave = tid >> 6;            // 0..3
    const int wm = (wave & 1) * 64;
    const int wn = (wave >> 1) * 64;
    const int bm = blockIdx.y * GTM;
    const int bn = blockIdx.x * GTN;
    const int kbase = blockIdx.z * K;     // split-K base (K = slice length)

    floatx4 acc[4][4];
#pragma unroll
    for (int i = 0; i < 4; ++i)
#pragma unroll
        for (int j = 0; j < 4; ++j) acc[i][j] = (floatx4){0.f, 0.f, 0.f, 0.f};

    const int srow = wave * 16 + (lane >> 2);   // 0..63 (per pass)
    const int scol = (lane & 3) * 8;            // bf16 col within k-tile
    const int fm = lane & 15;
    const int q  = lane >> 4;

    for (int k0 = 0; k0 < K; k0 += GTK) {
#pragma unroll
        for (int r = 0; r < 2; ++r) {
            const int m = r * 64 + srow;
            gload16(A + (size_t)(bm + m) * lda + kbase + k0 + scol,
                    As + m * GTK + scol);
            gload16(B + (size_t)(bn + m) * ldb + kbase + k0 + scol,
                    Bs + m * GTK + scol);
        }
        __syncthreads();

        short8 af[4], bfr[4];
#pragma unroll
        for (int i = 0; i < 4; ++i)
            af[i] = *(short8*)&As[(wm + i * 16 + fm) * GTK + q * 8];
#pragma unroll
        for (int j = 0; j < 4; ++j)
            bfr[j] = *(short8*)&Bs[(wn + j * 16 + fm) * GTK + q * 8];
#pragma unroll
        for (int i = 0; i < 4; ++i)
#pragma unroll
            for (int j = 0; j < 4; ++j)
                acc[i][j] = __builtin_amdgcn_mfma_f32_16x16x32_bf16(
                    af[i], bfr[j], acc[i][j], 0, 0, 0);
        __syncthreads();
    }

    // C/D layout: col=lane&15, row=(lane>>4)*4+reg  [m89/m91-verified]
    const int col = lane & 15;
    const int rq  = (lane >> 4) * 4;
#pragma unroll
    for (int i = 0; i < 4; ++i) {
#pragma unroll
        for (int j = 0; j < 4; ++j) {
#pragma unroll
            for (int r = 0; r < 4; ++r) {
                const int gm = bm + wm + i * 16 + rq + r;
                const int gn = bn + wn + j * 16 + col;
                if (gn >= N) continue;
                float v = acc[i][j][r];
                if (epi == 1) {
                    C[(size_t)gm * ldc + gn] = fsoftp(v + bias[gn]);
                } else if (epi == 2) {
                    C[(size_t)gm * ldc + gn] = v + resid[(size_t)gm * ldc + gn];
                } else if (epi == 3) {
                    atomicAdd(&C[(size_t)gm * ldc + gn], v);
                } else {
                    if (gn < D_INNER) C[(size_t)gm * ldc + gn] = v;
                    else C2[(size_t)gm * (size_t)D_INNER + (gn - D_INNER)] = f2b(v);
                }
            }
        }
    }
}

// ------------- conv(4)+SiLU from contiguous uraw; fp32 + bf16 out -----------
__global__ __launch_bounds__(256) void conv_par3(
    const float* __restrict__ uraw, const float* __restrict__ cw,
    const float* __restrict__ cb, float* __restrict__ uc, bf16* __restrict__ ucb)
{
    const int id = blockIdx.x * 256 + threadIdx.x;  // = (b*LL+t)*D_INNER+d
    const int d = id & (D_INNER - 1);
    const int t = (id >> 11) & (LL - 1);
    float acc = cb[d];
#pragma unroll
    for (int k = 0; k < 4; ++k) {
        const int tt = t - 3 + k;
        if (tt >= 0) acc += uraw[(size_t)id + (size_t)(k - 3) * D_INNER] * cw[d * 4 + k];
    }
    const float s = acc * fsig(acc);
    uc[id] = s;
    ucb[id] = f2b(s);
}

// ------------- dbl[:, :64] -> bf16 dt_r copy for GEMM-5 ----------------------
__global__ __launch_bounds__(256) void cvt_dtr(
    const float* __restrict__ dbl, bf16* __restrict__ dtr_bf)
{
    const int id = blockIdx.x * 256 + threadIdx.x;  // m*64+r
    const int m = id >> 6, r = id & 63;
    dtr_bf[id] = f2b(dbl[(size_t)m * DBL_LD + r]);
}

// ------------------------------ 3-phase scan ---------------------------------
__global__ __launch_bounds__(256) void scan_p1(
    const float* __restrict__ uc, const float* __restrict__ dtb,
    const float* __restrict__ dbl, const float* __restrict__ A_log,
    float* __restrict__ Psum, float* __restrict__ Hloc)
{
    const int blk = blockIdx.x;
    const int d = (blk & 7) * 256 + threadIdx.x;
    const int c = (blk >> 3) & (NCH - 1);
    const int b = blk >> 8;
    float A[D_STATE], h[D_STATE];
#pragma unroll
    for (int n = 0; n < D_STATE; ++n) {
        A[n] = -__expf(A_log[d * D_STATE + n]);
        h[n] = 0.f;
    }
    const size_t row0 = (size_t)b * LL + c * TCH;
    const float* dtp = dtb + row0 * D_INNER + d;
    const float* up  = uc  + row0 * D_INNER + d;
    const float* Bp  = dbl + row0 * DBL_LD + DT_RANK;
    float S = 0.f;
    for (int t = 0; t < TCH; ++t) {
        const float dtv = dtp[(size_t)t * D_INNER];
        const float uv  = up[(size_t)t * D_INNER];
        const float du  = dtv * uv;
        S += dtv;
#pragma unroll
        for (int n = 0; n < D_STATE; ++n)
            h[n] = __expf(dtv * A[n]) * h[n] + du * Bp[(size_t)t * DBL_LD + n];
    }
    const size_t o = (((size_t)b * NCH + c) * D_INNER + d) * D_STATE;
#pragma unroll
    for (int n = 0; n < D_STATE; ++n) {
        Psum[o + n] = __expf(S * A[n]);
        Hloc[o + n] = h[n];
    }
}

__global__ __launch_bounds__(256) void scan_p2(
    float* __restrict__ Psum, const float* __restrict__ Hloc)
{
    const int id = blockIdx.x * 256 + threadIdx.x;
    const int dn = id & (D_INNER * D_STATE - 1);
    const int b  = id >> 15;
    float h = 0.f;
    for (int c = 0; c < NCH; ++c) {
        const size_t o = ((size_t)(b * NCH + c) * D_INNER * D_STATE) + dn;
        const float P  = Psum[o];
        const float hl = Hloc[o];
        Psum[o] = h;          // Hin for chunk c
        h = P * h + hl;
    }
}

__global__ __launch_bounds__(256) void scan_p3b(
    const float* __restrict__ uc, const float* __restrict__ dtb,
    const float* __restrict__ dbl, const float* __restrict__ A_log,
    const float* __restrict__ Dw, const float* __restrict__ Hin,
    const bf16* __restrict__ zbf, bf16* __restrict__ ybf)
{
    const int blk = blockIdx.x;
    const int d = (blk & 7) * 256 + threadIdx.x;
    const int c = (blk >> 3) & (NCH - 1);
    const int b = blk >> 8;
    float A[D_STATE], h[D_STATE];
    const size_t o = (((size_t)b * NCH + c) * D_INNER + d) * D_STATE;
#pragma unroll
    for (int n = 0; n < D_STATE; ++n) {
        A[n] = -__expf(A_log[d * D_STATE + n]);
        h[n] = Hin[o + n];
    }
    const float Dd = Dw[d];
    const size_t row0 = (size_t)b * LL + c * TCH;
    const float* dtp = dtb + row0 * D_INNER + d;
    const float* up  = uc  + row0 * D_INNER + d;
    const float* BCp = dbl + row0 * DBL_LD;
    const bf16* zp   = zbf + row0 * D_INNER + d;
    bf16* yp         = ybf + row0 * D_INNER + d;
    for (int t = 0; t < TCH; ++t) {
        const float dtv = dtp[(size_t)t * D_INNER];
        const float uv  = up[(size_t)t * D_INNER];
        const float du  = dtv * uv;
        float acc = uv * Dd;
        const float* Brow = BCp + (size_t)t * DBL_LD + DT_RANK;
        const float* Crow = Brow + D_STATE;
#pragma unroll
        for (int n = 0; n < D_STATE; ++n) {
            h[n] = __expf(dtv * A[n]) * h[n] + du * Brow[n];
            acc += h[n] * Crow[n];
        }
        const float zv = (float)zp[(size_t)t * D_INNER];
        yp[(size_t)t * D_INNER] = f2b(acc * zv * fsig(zv));
    }
}

// ---------------- fallback (small ws): R4 sequential path --------------------
#define BM 128
#define BN 128
#define BK 8

__global__ __launch_bounds__(256) void gemm_bt(
    const float* __restrict__ A, int lda,
    const float* __restrict__ Bw,
    float* __restrict__ C, int ldc,
    int M, int N, int K, int epi,
    const float* __restrict__ bias,
    const float* __restrict__ resid)
{
    __shared__ float As[BK][BM + 1];
    __shared__ float Bs[BK][BN + 1];
    const int tx = threadIdx.x, ty = threadIdx.y;
    const int tid = ty * 16 + tx;
    const int bm = blockIdx.y * BM, bn = blockIdx.x * BN;
    float acc[8][8];
#pragma unroll
    for (int i = 0; i < 8; ++i)
#pragma unroll
        for (int j = 0; j < 8; ++j) acc[i][j] = 0.f;
    for (int k0 = 0; k0 < K; k0 += BK) {
#pragma unroll
        for (int i = tid; i < BM * BK; i += 256) {
            const int m = i / BK, kk = i % BK;
            As[kk][m] = A[(size_t)(bm + m) * lda + (k0 + kk)];
        }
#pragma unroll
        for (int i = tid; i < BN * BK; i += 256) {
            const int n = i / BK, kk = i % BK;
            const int gn = bn + n;
            Bs[kk][n] = (gn < N) ? Bw[(size_t)gn * K + (k0 + kk)] : 0.f;
        }
        __syncthreads();
#pragma unroll
        for (int kk = 0; kk < BK; ++kk) {
            float av[8], bv[8];
#pragma unroll
            for (int i = 0; i < 8; ++i) av[i] = As[kk][ty * 8 + i];
#pragma unroll
            for (int j = 0; j < 8; ++j) bv[j] = Bs[kk][tx * 8 + j];
#pragma unroll
            for (int i = 0; i < 8; ++i)
#pragma unroll
                for (int j = 0; j < 8; ++j) acc[i][j] += av[i] * bv[j];
        }
        __syncthreads();
    }
#pragma unroll
    for (int i = 0; i < 8; ++i) {
        const int gm = bm + ty * 8 + i;
#pragma unroll
        for (int j = 0; j < 8; ++j) {
            const int gn = bn + tx * 8 + j;
            if (gn >= N) continue;
            float v = acc[i][j];
            if (epi == 1) {
                v += bias[gn];
                v = fmaxf(v, 0.f) + log1pf(expf(-fabsf(v)));
            } else if (epi == 2) {
                v += resid[(size_t)gm * ldc + gn];
            }
            C[(size_t)gm * ldc + gn] = v;
        }
    }
}

__global__ __launch_bounds__(256) void conv_silu_kernel(
    float* __restrict__ xz, const float* __restrict__ cw,
    const float* __restrict__ cb)
{
    const int idx = blockIdx.x * 256 + threadIdx.x;
    const int b = idx >> 11, d = idx & (D_INNER - 1);
    const float w0 = cw[d * 4 + 0], w1 = cw[d * 4 + 1];
    const float w2 = cw[d * 4 + 2], w3 = cw[d * 4 + 3];
    const float bias = cb[d];
    float* u = xz + (size_t)b * LL * XZ_LD + d;
    float x0 = 0.f, x1 = 0.f, x2 = 0.f;
    for (int t = 0; t < LL; ++t) {
        const float x3 = u[(size_t)t * XZ_LD];
        const float c = bias + x0 * w0 + x1 * w1 + x2 * w2 + x3 * w3;
        u[(size_t)t * XZ_LD] = c / (1.f + expf(-c));
        x0 = x1; x1 = x2; x2 = x3;
    }
}

__global__ __launch_bounds__(256) void scan_kernel(
    float* __restrict__ xz, const float* __restrict__ dtb,
    const float* __restrict__ dbl,
    const float* __restrict__ A_log, const float* __restrict__ Dw)
{
    const int idx = blockIdx.x * 256 + threadIdx.x;
    const int b = idx >> 11, d = idx & (D_INNER - 1);
    float A[D_STATE], h[D_STATE];
#pragma unroll
    for (int n = 0; n < D_STATE; ++n) {
        A[n] = -expf(A_log[d * D_STATE + n]);
        h[n] = 0.f;
    }
    const float Dd = Dw[d];
    const float* dtp  = dtb + (size_t)b * LL * D_INNER + d;
    float*       up   = xz  + (size_t)b * LL * XZ_LD + d;
    const float* dblp = dbl + (size_t)b * LL * DBL_LD;
    for (int t = 0; t < LL; ++t) {
        const float dtv = dtp[(size_t)t * D_INNER];
        const float uv  = up[(size_t)t * XZ_LD];
        const float zv  = up[(size_t)t * XZ_LD + D_INNER];
        const float* Brow = dblp + (size_t)t * DBL_LD + DT_RANK;
        const float* Crow = Brow + D_STATE;
        const float du = dtv * uv;
        float acc = uv * Dd;
#pragma unroll
        for (int n = 0; n < D_STATE; ++n) {
            const float dA = expf(dtv * A[n]);
            h[n] = dA * h[n] + du * Brow[n];
            acc += h[n] * Crow[n];
        }
        const float sz = zv / (1.f + expf(-zv));
        up[(size_t)t * XZ_LD] = acc * sz;
    }
}

extern "C" void kernel_launch(void* const* d_in, const int* in_sizes, int n_in,
                              void* d_out, int out_size, void* d_ws, size_t ws_size,
                              hipStream_t stream)
{
    const float* x       = (const float*)d_in[0];
    const float* ln_w    = (const float*)d_in[1];
    const float* ln_b    = (const float*)d_in[2];
    const float* W_in    = (const float*)d_in[3];
    const float* conv_w  = (const float*)d_in[4];
    const float* conv_b  = (const float*)d_in[5];
    const float* W_xproj = (const float*)d_in[6];
    const float* W_dt    = (const float*)d_in[7];
    const float* b_dt    = (const float*)d_in[8];
    const float* A_log   = (const float*)d_in[9];
    const float* Dw      = (const float*)d_in[10];
    const float* W_out   = (const float*)d_in[11];
    float* out = (float*)d_out;

    // big-path ws layout (float offsets from base):
    //   dtb   [0,        8388608)   dt; early alias: xn_bf | win_bf
    //   uraw  [8388608, 16777216)   G2 u-out; later alias: Psum|Hloc|dtr_bf
    //   zbf   [16777216, 20971520)  bf16 z (4194304 f)
    //   dbl   [20971520, 21364736)
    //   uc    [21364736, 29753344)
    //   ucy   [29753344, 33947648)  bf16 uc, then bf16 y
    //   wx_bf [33947648, ..) wdt_bf wout_bf -> end 35192832 f = 134.3 MiB
    float* wsf    = (float*)d_ws;
    float* dtb    = wsf;
    bf16*  xn_bf  = (bf16*)dtb;
    bf16*  win_bf = (bf16*)(dtb + 2097152);
    float* uraw   = wsf + 8388608;
    float* Psum   = uraw;
    float* Hloc   = uraw + 2097152;
    bf16*  dtr_bf = (bf16*)(uraw + 4194304);
    bf16*  zbf    = (bf16*)(wsf + 16777216);
    float* dbl    = wsf + 20971520;
    float* uc     = wsf + 21364736;
    bf16*  ucy    = (bf16*)(wsf + 29753344);
    bf16*  wx_bf  = (bf16*)(wsf + 33947648);
    bf16*  wdt_bf = wx_bf + S1;
    bf16*  wout_bf= wdt_bf + S2;
    const size_t need_big = (size_t)35192832 * sizeof(float);

    if (ws_size >= need_big) {
        // out := x FIRST, so the dirty lines drain during wcvt+ln (L2 hygiene:
        // running this right before G2 cost G2 +33% in R9).
        init_out<<<BL * D_MODEL / 4 / 256, 256, 0, stream>>>(x, out);
        wcvt_kernel<<<(S0 + S1 + S2 + S3 + S4) / 256, 256, 0, stream>>>(
            W_in, W_xproj, W_dt, W_out, win_bf, wx_bf, wdt_bf, wout_bf, dbl);
        ln_kernel<<<BL, 256, 0, stream>>>(x, ln_w, ln_b, nullptr, xn_bf);
        // G2: [u|z] = xn @ W_in^T  (M=4096, N=4096, K=1024)
        gemm_bf<<<dim3(XZ_LD / GTN, BL / GTM, 1), 256, 0, stream>>>(
            xn_bf, D_MODEL, win_bf, D_MODEL, uraw, D_INNER,
            XZ_LD, D_MODEL, 4, nullptr, nullptr, zbf);
        conv_par3<<<(size_t)BL * D_INNER / 256, 256, 0, stream>>>(
            uraw, conv_w, conv_b, uc, ucy);
        // G4: dbl += uc @ W_xproj^T  (N=96 pad 128, split-K=8, atomic)
        gemm_bf<<<dim3(1, BL / GTM, 8), 256, 0, stream>>>(
            ucy, D_INNER, wx_bf, D_INNER, dbl, DBL_LD,
            DBL_LD, D_INNER / 8, 3, nullptr, nullptr, nullptr);
        cvt_dtr<<<BL * DT_RANK / 256, 256, 0, stream>>>(dbl, dtr_bf);
        // G5: dt = softplus(dt_r @ W_dt^T + b_dt)  (N=2048, K=64)
        gemm_bf<<<dim3(D_INNER / GTN, BL / GTM, 1), 256, 0, stream>>>(
            dtr_bf, DT_RANK, wdt_bf, DT_RANK, dtb, D_INNER,
            D_INNER, DT_RANK, 1, b_dt, nullptr, nullptr);
        scan_p1<<<BB * NCH * 8, 256, 0, stream>>>(uc, dtb, dbl, A_log, Psum, Hloc);
        scan_p2<<<BB * D_INNER * D_STATE / 256, 256, 0, stream>>>(Psum, Hloc);
        scan_p3b<<<BB * NCH * 8, 256, 0, stream>>>(
            uc, dtb, dbl, A_log, Dw, Psum, zbf, ucy);
        // G7: out += y @ W_out^T  (N=1024, split-K=4, atomic; out pre-init to x)
        gemm_bf<<<dim3(D_MODEL / GTN, BL / GTM, 4), 256, 0, stream>>>(
            ucy, D_INNER, wout_bf, D_INNER, out, D_MODEL,
            D_MODEL, D_INNER / 4, 3, nullptr, nullptr, nullptr);
    } else {
        float* fdtb = wsf;
        float* fxn  = fdtb;
        float* fxz  = fdtb + (size_t)BL * D_INNER;
        float* fdbl = fxz + (size_t)BL * XZ_LD;
        ln_kernel<<<BL, 256, 0, stream>>>(x, ln_w, ln_b, fxn, nullptr);
        dim3 blk(16, 16);
        gemm_bt<<<dim3(XZ_LD / BN, BL / BM), blk, 0, stream>>>(
            fxn, D_MODEL, W_in, fxz, XZ_LD, BL, XZ_LD, D_MODEL, 0, nullptr, nullptr);
        conv_silu_kernel<<<(BB * D_INNER) / 256, 256, 0, stream>>>(fxz, conv_w, conv_b);
        gemm_bt<<<dim3(1, BL / BM), blk, 0, stream>>>(
            fxz, XZ_LD, W_xproj, fdbl, DBL_LD, BL, DBL_LD, D_INNER, 0, nullptr, nullptr);
        gemm_bt<<<dim3(D_INNER / BN, BL / BM), blk, 0, stream>>>(
            fdbl, DBL_LD, W_dt, fdtb, D_INNER, BL, D_INNER, DT_RANK, 1, b_dt, nullptr);
        scan_kernel<<<(BB * D_INNER) / 256, 256, 0, stream>>>(fxz, fdtb, fdbl, A_log, Dw);
        gemm_bt<<<dim3(D_MODEL / BN, BL / BM), blk, 0, stream>>>(
            fxz, XZ_LD, W_out, out, D_MODEL, BL, D_MODEL, D_INNER, 2, nullptr, x);
    }
}

// Round 12
// 408.166 us; speedup vs baseline: 1.0594x; 1.0594x over previous
//
#include <hip/hip_runtime.h>
#include <hip/hip_bf16.h>
#include <stdint.h>

typedef __hip_bfloat16 bf16;
typedef __attribute__((ext_vector_type(8))) short short8;
typedef __attribute__((ext_vector_type(4))) float floatx4;

#define D_MODEL 1024
#define D_STATE 16
#define D_INNER 2048
#define DT_RANK 64
#define BB 2
#define LL 2048
#define BL (BB * LL)            // 4096 rows
#define XZ_LD (2 * D_INNER)     // 4096 (fallback path only)
#define DBL_LD (DT_RANK + 2 * D_STATE)  // 96
#define NCH 64                  // time chunks for parallel scan (R12: 32->64)
#define TCH (LL / NCH)          // 32 steps per chunk

__device__ __forceinline__ bf16 f2b(float f) { return __float2bfloat16(f); }

// fast sigmoid / softplus via native v_exp/v_log/v_rcp (~3e-7 rel err)
__device__ __forceinline__ float fsig(float v)  { return __fdividef(1.f, 1.f + __expf(-v)); }
__device__ __forceinline__ float fsoftp(float v){ return fmaxf(v, 0.f) + __logf(1.f + __expf(-fabsf(v))); }

// async 16B global -> LDS (wave-uniform LDS base + lane*16; rows contiguous)
__device__ __forceinline__ void gload16(const void* g, void* l) {
    __builtin_amdgcn_global_load_lds(
        (const __attribute__((address_space(1))) uint32_t*)(uintptr_t)g,
        (__attribute__((address_space(3))) uint32_t*)(uintptr_t)l,
        16, 0, 0);
}

// ---------------- LayerNorm: one block per row; bf16 and/or fp32 out ---------
__global__ __launch_bounds__(256) void ln_kernel(
    const float* __restrict__ x, const float* __restrict__ w,
    const float* __restrict__ b, float* __restrict__ xnf, bf16* __restrict__ xnb)
{
    __shared__ float s1[256], s2[256];
    const int row = blockIdx.x;
    const int tid = threadIdx.x;
    const float* xr = x + (size_t)row * D_MODEL;
    float v[4], sum = 0.f, sq = 0.f;
#pragma unroll
    for (int i = 0; i < 4; ++i) {
        v[i] = xr[tid + 256 * i];
        sum += v[i];
        sq  += v[i] * v[i];
    }
    s1[tid] = sum; s2[tid] = sq;
    __syncthreads();
    for (int s = 128; s > 0; s >>= 1) {
        if (tid < s) { s1[tid] += s1[tid + s]; s2[tid] += s2[tid + s]; }
        __syncthreads();
    }
    const float mu  = s1[0] * (1.f / D_MODEL);
    const float var = s2[0] * (1.f / D_MODEL) - mu * mu;
    const float rs  = rsqrtf(var + 1e-5f);
#pragma unroll
    for (int i = 0; i < 4; ++i) {
        const int c = tid + 256 * i;
        const float r = (v[i] - mu) * rs * w[c] + b[c];
        if (xnb) xnb[(size_t)row * D_MODEL + c] = f2b(r);
        if (xnf) xnf[(size_t)row * D_MODEL + c] = r;
    }
}

// ------------- out pre-init with residual x (for G7 split-K atomics) ---------
// launched FIRST so its dirty L2 lines drain during wcvt+ln, not during G2.
__global__ __launch_bounds__(256) void init_out(
    const float* __restrict__ x, float* __restrict__ out)
{
    const int id = blockIdx.x * 256 + threadIdx.x;
    ((float4*)out)[id] = ((const float4*)x)[id];
}

// --------- fused fp32->bf16 weight conversion (+pad W_xproj, +zero dbl) ------
#define S0 (4096 * 1024)   // W_in
#define S1 (128 * 2048)    // W_xproj padded to 128 rows
#define S2 (2048 * 64)     // W_dt
#define S3 (1024 * 2048)   // W_out
#define S4 (BL * DBL_LD)   // dbl zero-init (for split-K atomics)

__global__ __launch_bounds__(256) void wcvt_kernel(
    const float* __restrict__ Win, const float* __restrict__ Wx,
    const float* __restrict__ Wdt, const float* __restrict__ Wout,
    bf16* __restrict__ win_bf, bf16* __restrict__ wx_bf,
    bf16* __restrict__ wdt_bf, bf16* __restrict__ wout_bf,
    float* __restrict__ dbl)
{
    int id = blockIdx.x * 256 + threadIdx.x;
    if (id < S0) { win_bf[id] = f2b(Win[id]); return; }
    id -= S0;
    if (id < S1) { wx_bf[id] = (id < 96 * 2048) ? f2b(Wx[id]) : f2b(0.f); return; }
    id -= S1;
    if (id < S2) { wdt_bf[id] = f2b(Wdt[id]); return; }
    id -= S2;
    if (id < S3) { wout_bf[id] = f2b(Wout[id]); return; }
    id -= S3;
    dbl[id] = 0.f;
}

// ============ bf16 MFMA GEMM (R9-proven, BK=32): C = A[M,K] * B[N,K]^T =======
// epi: 1=+bias softplus; 2=+resid; 3=atomicAdd (split-K, K=slice len);
//      4=u/z split (gn<D_INNER -> fp32 C, else bf16 C2)
#define GTM 128
#define GTN 128
#define GTK 32

__global__ __launch_bounds__(256) void gemm_bf(
    const bf16* __restrict__ A, int lda,
    const bf16* __restrict__ B, int ldb,
    float* __restrict__ C, int ldc,
    int N, int K, int epi,
    const float* __restrict__ bias,
    const float* __restrict__ resid,
    bf16* __restrict__ C2)
{
    __shared__ short As[GTM * GTK];   // 8 KB
    __shared__ short Bs[GTN * GTK];   // 8 KB
    const int tid  = threadIdx.x;
    const int lane = tid & 63;
    const int wave = tid >> 6;            // 0..3
    const int wm = (wave & 1) * 64;
    const int wn = (wave >> 1) * 64;
    const int bm = blockIdx.y * GTM;
    const int bn = blockIdx.x * GTN;
    const int kbase = blockIdx.z * K;     // split-K base (K = slice length)

    floatx4 acc[4][4];
#pragma unroll
    for (int i = 0; i < 4; ++i)
#pragma unroll
        for (int j = 0; j < 4; ++j) acc[i][j] = (floatx4){0.f, 0.f, 0.f, 0.f};

    const int srow = wave * 16 + (lane >> 2);   // 0..63 (per pass)
    const int scol = (lane & 3) * 8;            // bf16 col within k-tile
    const int fm = lane & 15;
    const int q  = lane >> 4;

    for (int k0 = 0; k0 < K; k0 += GTK) {
#pragma unroll
        for (int r = 0; r < 2; ++r) {
            const int m = r * 64 + srow;
            gload16(A + (size_t)(bm + m) * lda + kbase + k0 + scol,
                    As + m * GTK + scol);
            gload16(B + (size_t)(bn + m) * ldb + kbase + k0 + scol,
                    Bs + m * GTK + scol);
        }
        __syncthreads();

        short8 af[4], bfr[4];
#pragma unroll
        for (int i = 0; i < 4; ++i)
            af[i] = *(short8*)&As[(wm + i * 16 + fm) * GTK + q * 8];
#pragma unroll
        for (int j = 0; j < 4; ++j)
            bfr[j] = *(short8*)&Bs[(wn + j * 16 + fm) * GTK + q * 8];
#pragma unroll
        for (int i = 0; i < 4; ++i)
#pragma unroll
            for (int j = 0; j < 4; ++j)
                acc[i][j] = __builtin_amdgcn_mfma_f32_16x16x32_bf16(
                    af[i], bfr[j], acc[i][j], 0, 0, 0);
        __syncthreads();
    }

    // C/D layout: col=lane&15, row=(lane>>4)*4+reg  [m89/m91-verified]
    const int col = lane & 15;
    const int rq  = (lane >> 4) * 4;
#pragma unroll
    for (int i = 0; i < 4; ++i) {
#pragma unroll
        for (int j = 0; j < 4; ++j) {
#pragma unroll
            for (int r = 0; r < 4; ++r) {
                const int gm = bm + wm + i * 16 + rq + r;
                const int gn = bn + wn + j * 16 + col;
                if (gn >= N) continue;
                float v = acc[i][j][r];
                if (epi == 1) {
                    C[(size_t)gm * ldc + gn] = fsoftp(v + bias[gn]);
                } else if (epi == 2) {
                    C[(size_t)gm * ldc + gn] = v + resid[(size_t)gm * ldc + gn];
                } else if (epi == 3) {
                    atomicAdd(&C[(size_t)gm * ldc + gn], v);
                } else {
                    if (gn < D_INNER) C[(size_t)gm * ldc + gn] = v;
                    else C2[(size_t)gm * (size_t)D_INNER + (gn - D_INNER)] = f2b(v);
                }
            }
        }
    }
}

// ------------- conv(4)+SiLU from contiguous uraw; fp32 + bf16 out -----------
__global__ __launch_bounds__(256) void conv_par3(
    const float* __restrict__ uraw, const float* __restrict__ cw,
    const float* __restrict__ cb, float* __restrict__ uc, bf16* __restrict__ ucb)
{
    const int id = blockIdx.x * 256 + threadIdx.x;  // = (b*LL+t)*D_INNER+d
    const int d = id & (D_INNER - 1);
    const int t = (id >> 11) & (LL - 1);
    float acc = cb[d];
#pragma unroll
    for (int k = 0; k < 4; ++k) {
        const int tt = t - 3 + k;
        if (tt >= 0) acc += uraw[(size_t)id + (size_t)(k - 3) * D_INNER] * cw[d * 4 + k];
    }
    const float s = acc * fsig(acc);
    uc[id] = s;
    ucb[id] = f2b(s);
}

// ------------- dbl[:, :64] -> bf16 dt_r copy for GEMM-5 ----------------------
__global__ __launch_bounds__(256) void cvt_dtr(
    const float* __restrict__ dbl, bf16* __restrict__ dtr_bf)
{
    const int id = blockIdx.x * 256 + threadIdx.x;  // m*64+r
    const int m = id >> 6, r = id & 63;
    dtr_bf[id] = f2b(dbl[(size_t)m * DBL_LD + r]);
}

// ------------------------------ 3-phase scan ---------------------------------
// block decode: blk = ((b*NCH)+c)*8 + dgrp ; d = dgrp*256 + tid
__global__ __launch_bounds__(256) void scan_p1(
    const float* __restrict__ uc, const float* __restrict__ dtb,
    const float* __restrict__ dbl, const float* __restrict__ A_log,
    float* __restrict__ Psum, float* __restrict__ Hloc)
{
    const int blk = blockIdx.x;
    const int d = (blk & 7) * 256 + threadIdx.x;
    const int c = (blk >> 3) & (NCH - 1);
    const int b = blk >> 9;                  // NCH=64 -> 9 bits below b
    float A[D_STATE], h[D_STATE];
#pragma unroll
    for (int n = 0; n < D_STATE; ++n) {
        A[n] = -__expf(A_log[d * D_STATE + n]);
        h[n] = 0.f;
    }
    const size_t row0 = (size_t)b * LL + c * TCH;
    const float* dtp = dtb + row0 * D_INNER + d;
    const float* up  = uc  + row0 * D_INNER + d;
    const float* Bp  = dbl + row0 * DBL_LD + DT_RANK;
    float S = 0.f;
    for (int t = 0; t < TCH; ++t) {
        const float dtv = dtp[(size_t)t * D_INNER];
        const float uv  = up[(size_t)t * D_INNER];
        const float du  = dtv * uv;
        S += dtv;
#pragma unroll
        for (int n = 0; n < D_STATE; ++n)
            h[n] = __expf(dtv * A[n]) * h[n] + du * Bp[(size_t)t * DBL_LD + n];
    }
    const size_t o = (((size_t)b * NCH + c) * D_INNER + d) * D_STATE;
#pragma unroll
    for (int n = 0; n < D_STATE; ++n) {
        Psum[o + n] = __expf(S * A[n]);
        Hloc[o + n] = h[n];
    }
}

__global__ __launch_bounds__(256) void scan_p2(
    float* __restrict__ Psum, const float* __restrict__ Hloc)
{
    const int id = blockIdx.x * 256 + threadIdx.x;
    const int dn = id & (D_INNER * D_STATE - 1);
    const int b  = id >> 15;
    float h = 0.f;
    for (int c = 0; c < NCH; ++c) {
        const size_t o = ((size_t)(b * NCH + c) * D_INNER * D_STATE) + dn;
        const float P  = Psum[o];
        const float hl = Hloc[o];
        Psum[o] = h;          // Hin for chunk c
        h = P * h + hl;
    }
}

__global__ __launch_bounds__(256) void scan_p3b(
    const float* __restrict__ uc, const float* __restrict__ dtb,
    const float* __restrict__ dbl, const float* __restrict__ A_log,
    const float* __restrict__ Dw, const float* __restrict__ Hin,
    const bf16* __restrict__ zbf, bf16* __restrict__ ybf)
{
    const int blk = blockIdx.x;
    const int d = (blk & 7) * 256 + threadIdx.x;
    const int c = (blk >> 3) & (NCH - 1);
    const int b = blk >> 9;                  // NCH=64 -> 9 bits below b
    float A[D_STATE], h[D_STATE];
    const size_t o = (((size_t)b * NCH + c) * D_INNER + d) * D_STATE;
#pragma unroll
    for (int n = 0; n < D_STATE; ++n) {
        A[n] = -__expf(A_log[d * D_STATE + n]);
        h[n] = Hin[o + n];
    }
    const float Dd = Dw[d];
    const size_t row0 = (size_t)b * LL + c * TCH;
    const float* dtp = dtb + row0 * D_INNER + d;
    const float* up  = uc  + row0 * D_INNER + d;
    const float* BCp = dbl + row0 * DBL_LD;
    const bf16* zp   = zbf + row0 * D_INNER + d;
    bf16* yp         = ybf + row0 * D_INNER + d;
    for (int t = 0; t < TCH; ++t) {
        const float dtv = dtp[(size_t)t * D_INNER];
        const float uv  = up[(size_t)t * D_INNER];
        const float du  = dtv * uv;
        float acc = uv * Dd;
        const float* Brow = BCp + (size_t)t * DBL_LD + DT_RANK;
        const float* Crow = Brow + D_STATE;
#pragma unroll
        for (int n = 0; n < D_STATE; ++n) {
            h[n] = __expf(dtv * A[n]) * h[n] + du * Brow[n];
            acc += h[n] * Crow[n];
        }
        const float zv = (float)zp[(size_t)t * D_INNER];
        yp[(size_t)t * D_INNER] = f2b(acc * zv * fsig(zv));
    }
}

// ---------------- fallback (small ws): R4 sequential path --------------------
#define BM 128
#define BN 128
#define BK 8

__global__ __launch_bounds__(256) void gemm_bt(
    const float* __restrict__ A, int lda,
    const float* __restrict__ Bw,
    float* __restrict__ C, int ldc,
    int M, int N, int K, int epi,
    const float* __restrict__ bias,
    const float* __restrict__ resid)
{
    __shared__ float As[BK][BM + 1];
    __shared__ float Bs[BK][BN + 1];
    const int tx = threadIdx.x, ty = threadIdx.y;
    const int tid = ty * 16 + tx;
    const int bm = blockIdx.y * BM, bn = blockIdx.x * BN;
    float acc[8][8];
#pragma unroll
    for (int i = 0; i < 8; ++i)
#pragma unroll
        for (int j = 0; j < 8; ++j) acc[i][j] = 0.f;
    for (int k0 = 0; k0 < K; k0 += BK) {
#pragma unroll
        for (int i = tid; i < BM * BK; i += 256) {
            const int m = i / BK, kk = i % BK;
            As[kk][m] = A[(size_t)(bm + m) * lda + (k0 + kk)];
        }
#pragma unroll
        for (int i = tid; i < BN * BK; i += 256) {
            const int n = i / BK, kk = i % BK;
            const int gn = bn + n;
            Bs[kk][n] = (gn < N) ? Bw[(size_t)gn * K + (k0 + kk)] : 0.f;
        }
        __syncthreads();
#pragma unroll
        for (int kk = 0; kk < BK; ++kk) {
            float av[8], bv[8];
#pragma unroll
            for (int i = 0; i < 8; ++i) av[i] = As[kk][ty * 8 + i];
#pragma unroll
            for (int j = 0; j < 8; ++j) bv[j] = Bs[kk][tx * 8 + j];
#pragma unroll
            for (int i = 0; i < 8; ++i)
#pragma unroll
                for (int j = 0; j < 8; ++j) acc[i][j] += av[i] * bv[j];
        }
        __syncthreads();
    }
#pragma unroll
    for (int i = 0; i < 8; ++i) {
        const int gm = bm + ty * 8 + i;
#pragma unroll
        for (int j = 0; j < 8; ++j) {
            const int gn = bn + tx * 8 + j;
            if (gn >= N) continue;
            float v = acc[i][j];
            if (epi == 1) {
                v += bias[gn];
                v = fmaxf(v, 0.f) + log1pf(expf(-fabsf(v)));
            } else if (epi == 2) {
                v += resid[(size_t)gm * ldc + gn];
            }
            C[(size_t)gm * ldc + gn] = v;
        }
    }
}

__global__ __launch_bounds__(256) void conv_silu_kernel(
    float* __restrict__ xz, const float* __restrict__ cw,
    const float* __restrict__ cb)
{
    const int idx = blockIdx.x * 256 + threadIdx.x;
    const int b = idx >> 11, d = idx & (D_INNER - 1);
    const float w0 = cw[d * 4 + 0], w1 = cw[d * 4 + 1];
    const float w2 = cw[d * 4 + 2], w3 = cw[d * 4 + 3];
    const float bias = cb[d];
    float* u = xz + (size_t)b * LL * XZ_LD + d;
    float x0 = 0.f, x1 = 0.f, x2 = 0.f;
    for (int t = 0; t < LL; ++t) {
        const float x3 = u[(size_t)t * XZ_LD];
        const float c = bias + x0 * w0 + x1 * w1 + x2 * w2 + x3 * w3;
        u[(size_t)t * XZ_LD] = c / (1.f + expf(-c));
        x0 = x1; x1 = x2; x2 = x3;
    }
}

__global__ __launch_bounds__(256) void scan_kernel(
    float* __restrict__ xz, const float* __restrict__ dtb,
    const float* __restrict__ dbl,
    const float* __restrict__ A_log, const float* __restrict__ Dw)
{
    const int idx = blockIdx.x * 256 + threadIdx.x;
    const int b = idx >> 11, d = idx & (D_INNER - 1);
    float A[D_STATE], h[D_STATE];
#pragma unroll
    for (int n = 0; n < D_STATE; ++n) {
        A[n] = -expf(A_log[d * D_STATE + n]);
        h[n] = 0.f;
    }
    const float Dd = Dw[d];
    const float* dtp  = dtb + (size_t)b * LL * D_INNER + d;
    float*       up   = xz  + (size_t)b * LL * XZ_LD + d;
    const float* dblp = dbl + (size_t)b * LL * DBL_LD;
    for (int t = 0; t < LL; ++t) {
        const float dtv = dtp[(size_t)t * D_INNER];
        const float uv  = up[(size_t)t * XZ_LD];
        const float zv  = up[(size_t)t * XZ_LD + D_INNER];
        const float* Brow = dblp + (size_t)t * DBL_LD + DT_RANK;
        const float* Crow = Brow + D_STATE;
        const float du = dtv * uv;
        float acc = uv * Dd;
#pragma unroll
        for (int n = 0; n < D_STATE; ++n) {
            const float dA = expf(dtv * A[n]);
            h[n] = dA * h[n] + du * Brow[n];
            acc += h[n] * Crow[n];
        }
        const float sz = zv / (1.f + expf(-zv));
        up[(size_t)t * XZ_LD] = acc * sz;
    }
}

extern "C" void kernel_launch(void* const* d_in, const int* in_sizes, int n_in,
                              void* d_out, int out_size, void* d_ws, size_t ws_size,
                              hipStream_t stream)
{
    const float* x       = (const float*)d_in[0];
    const float* ln_w    = (const float*)d_in[1];
    const float* ln_b    = (const float*)d_in[2];
    const float* W_in    = (const float*)d_in[3];
    const float* conv_w  = (const float*)d_in[4];
    const float* conv_b  = (const float*)d_in[5];
    const float* W_xproj = (const float*)d_in[6];
    const float* W_dt    = (const float*)d_in[7];
    const float* b_dt    = (const float*)d_in[8];
    const float* A_log   = (const float*)d_in[9];
    const float* Dw      = (const float*)d_in[10];
    const float* W_out   = (const float*)d_in[11];
    float* out = (float*)d_out;

    // big-path ws layout (float offsets from base):
    //   dtb   [0,        8388608)   dt; early alias: xn_bf | win_bf
    //   uraw  [8388608, 16777216)   G2 u-out; later alias: Psum(4.19M)|Hloc(4.19M)
    //   zbf   [16777216, 20971520)  bf16 z (4194304 f)
    //   dbl   [20971520, 21364736)
    //   uc    [21364736, 29753344)
    //   ucy   [29753344, 33947648)  bf16 uc, then bf16 y
    //   wx_bf [33947648, ..) wdt_bf wout_bf -> 35192832
    //   dtr_bf[35192832, 35323904)  (moved out of uraw: NCH=64 fills it)
    // total = 35323904 f = 134.8 MiB  (< the >=145.5 MiB proven in R5)
    float* wsf    = (float*)d_ws;
    float* dtb    = wsf;
    bf16*  xn_bf  = (bf16*)dtb;
    bf16*  win_bf = (bf16*)(dtb + 2097152);
    float* uraw   = wsf + 8388608;
    float* Psum   = uraw;
    float* Hloc   = uraw + 4194304;
    bf16*  zbf    = (bf16*)(wsf + 16777216);
    float* dbl    = wsf + 20971520;
    float* uc     = wsf + 21364736;
    bf16*  ucy    = (bf16*)(wsf + 29753344);
    bf16*  wx_bf  = (bf16*)(wsf + 33947648);
    bf16*  wdt_bf = wx_bf + S1;
    bf16*  wout_bf= wdt_bf + S2;
    bf16*  dtr_bf = (bf16*)(wsf + 35192832);
    const size_t need_big = (size_t)35323904 * sizeof(float);

    if (ws_size >= need_big) {
        // out := x FIRST, so the dirty lines drain during wcvt+ln (L2 hygiene:
        // running this right before G2 cost G2 +33% in R9).
        init_out<<<BL * D_MODEL / 4 / 256, 256, 0, stream>>>(x, out);
        wcvt_kernel<<<(S0 + S1 + S2 + S3 + S4) / 256, 256, 0, stream>>>(
            W_in, W_xproj, W_dt, W_out, win_bf, wx_bf, wdt_bf, wout_bf, dbl);
        ln_kernel<<<BL, 256, 0, stream>>>(x, ln_w, ln_b, nullptr, xn_bf);
        // G2: [u|z] = xn @ W_in^T  (M=4096, N=4096, K=1024)
        gemm_bf<<<dim3(XZ_LD / GTN, BL / GTM, 1), 256, 0, stream>>>(
            xn_bf, D_MODEL, win_bf, D_MODEL, uraw, D_INNER,
            XZ_LD, D_MODEL, 4, nullptr, nullptr, zbf);
        conv_par3<<<(size_t)BL * D_INNER / 256, 256, 0, stream>>>(
            uraw, conv_w, conv_b, uc, ucy);
        // G4: dbl += uc @ W_xproj^T  (N=96 pad 128, split-K=8, atomic)
        gemm_bf<<<dim3(1, BL / GTM, 8), 256, 0, stream>>>(
            ucy, D_INNER, wx_bf, D_INNER, dbl, DBL_LD,
            DBL_LD, D_INNER / 8, 3, nullptr, nullptr, nullptr);
        cvt_dtr<<<BL * DT_RANK / 256, 256, 0, stream>>>(dbl, dtr_bf);
        // G5: dt = softplus(dt_r @ W_dt^T + b_dt)  (N=2048, K=64)
        gemm_bf<<<dim3(D_INNER / GTN, BL / GTM, 1), 256, 0, stream>>>(
            dtr_bf, DT_RANK, wdt_bf, DT_RANK, dtb, D_INNER,
            D_INNER, DT_RANK, 1, b_dt, nullptr, nullptr);
        // chunked scan, NCH=64 (16 waves/CU)
        scan_p1<<<BB * NCH * 8, 256, 0, stream>>>(uc, dtb, dbl, A_log, Psum, Hloc);
        scan_p2<<<BB * D_INNER * D_STATE / 256, 256, 0, stream>>>(Psum, Hloc);
        scan_p3b<<<BB * NCH * 8, 256, 0, stream>>>(
            uc, dtb, dbl, A_log, Dw, Psum, zbf, ucy);
        // G7: out += y @ W_out^T  (N=1024, split-K=2, atomic; out pre-init to x)
        gemm_bf<<<dim3(D_MODEL / GTN, BL / GTM, 2), 256, 0, stream>>>(
            ucy, D_INNER, wout_bf, D_INNER, out, D_MODEL,
            D_MODEL, D_INNER / 2, 3, nullptr, nullptr, nullptr);
    } else {
        float* fdtb = wsf;
        float* fxn  = fdtb;
        float* fxz  = fdtb + (size_t)BL * D_INNER;
        float* fdbl = fxz + (size_t)BL * XZ_LD;
        ln_kernel<<<BL, 256, 0, stream>>>(x, ln_w, ln_b, fxn, nullptr);
        dim3 blk(16, 16);
        gemm_bt<<<dim3(XZ_LD / BN, BL / BM), blk, 0, stream>>>(
            fxn, D_MODEL, W_in, fxz, XZ_LD, BL, XZ_LD, D_MODEL, 0, nullptr, nullptr);
        conv_silu_kernel<<<(BB * D_INNER) / 256, 256, 0, stream>>>(fxz, conv_w, conv_b);
        gemm_bt<<<dim3(1, BL / BM), blk, 0, stream>>>(
            fxz, XZ_LD, W_xproj, fdbl, DBL_LD, BL, DBL_LD, D_INNER, 0, nullptr, nullptr);
        gemm_bt<<<dim3(D_INNER / BN, BL / BM), blk, 0, stream>>>(
            fdbl, DBL_LD, W_dt, fdtb, D_INNER, BL, D_INNER, DT_RANK, 1, b_dt, nullptr);
        scan_kernel<<<(BB * D_INNER) / 256, 256, 0, stream>>>(fxz, fdtb, fdbl, A_log, Dw);
        gemm_bt<<<dim3(D_MODEL / BN, BL / BM), blk, 0, stream>>>(
            fxz, XZ_LD, W_out, out, D_MODEL, BL, D_MODEL, D_INNER, 2, nullptr, x);
    }
}

// Round 14
// 404.206 us; speedup vs baseline: 1.0698x; 1.0098x over previous
//
#include <hip/hip_runtime.h>
#include <hip/hip_bf16.h>
#include <stdint.h>

typedef __hip_bfloat16 bf16;
typedef __attribute__((ext_vector_type(8))) short short8;
typedef __attribute__((ext_vector_type(4))) float floatx4;

#define D_MODEL 1024
#define D_STATE 16
#define D_INNER 2048
#define DT_RANK 64
#define BB 2
#define LL 2048
#define BL (BB * LL)            // 4096 rows
#define XZ_LD (2 * D_INNER)     // 4096
#define DBL_LD (DT_RANK + 2 * D_STATE)  // 96
#define NCH 64                  // time chunks for parallel scan
#define TCH (LL / NCH)          // 32 steps per chunk

__device__ __forceinline__ bf16 f2b(float f) { return __float2bfloat16(f); }

// fast sigmoid / softplus via native v_exp/v_log/v_rcp (~3e-7 rel err)
__device__ __forceinline__ float fsig(float v)  { return __fdividef(1.f, 1.f + __expf(-v)); }
__device__ __forceinline__ float fsoftp(float v){ return fmaxf(v, 0.f) + __logf(1.f + __expf(-fabsf(v))); }

// async 16B global -> LDS (wave-uniform LDS base + lane*16; rows contiguous)
__device__ __forceinline__ void gload16(const void* g, void* l) {
    __builtin_amdgcn_global_load_lds(
        (const __attribute__((address_space(1))) uint32_t*)(uintptr_t)g,
        (__attribute__((address_space(3))) uint32_t*)(uintptr_t)l,
        16, 0, 0);
}

// ---------------- LayerNorm: one block per row; bf16 and/or fp32 out ---------
__global__ __launch_bounds__(256) void ln_kernel(
    const float* __restrict__ x, const float* __restrict__ w,
    const float* __restrict__ b, float* __restrict__ xnf, bf16* __restrict__ xnb)
{
    __shared__ float s1[256], s2[256];
    const int row = blockIdx.x;
    const int tid = threadIdx.x;
    const float* xr = x + (size_t)row * D_MODEL;
    float v[4], sum = 0.f, sq = 0.f;
#pragma unroll
    for (int i = 0; i < 4; ++i) {
        v[i] = xr[tid + 256 * i];
        sum += v[i];
        sq  += v[i] * v[i];
    }
    s1[tid] = sum; s2[tid] = sq;
    __syncthreads();
    for (int s = 128; s > 0; s >>= 1) {
        if (tid < s) { s1[tid] += s1[tid + s]; s2[tid] += s2[tid + s]; }
        __syncthreads();
    }
    const float mu  = s1[0] * (1.f / D_MODEL);
    const float var = s2[0] * (1.f / D_MODEL) - mu * mu;
    const float rs  = rsqrtf(var + 1e-5f);
#pragma unroll
    for (int i = 0; i < 4; ++i) {
        const int c = tid + 256 * i;
        const float r = (v[i] - mu) * rs * w[c] + b[c];
        if (xnb) xnb[(size_t)row * D_MODEL + c] = f2b(r);
        if (xnf) xnf[(size_t)row * D_MODEL + c] = r;
    }
}

// ------------- out pre-init with residual x (for G7 split-K atomics) ---------
// launched FIRST so its dirty L2 lines drain during wcvt+ln, not during G2.
__global__ __launch_bounds__(256) void init_out(
    const float* __restrict__ x, float* __restrict__ out)
{
    const int id = blockIdx.x * 256 + threadIdx.x;
    ((float4*)out)[id] = ((const float4*)x)[id];
}

// --------- fused fp32->bf16 weight conversion (+pad W_xproj, +zero dbl) ------
#define S0 (4096 * 1024)   // W_in
#define S1 (128 * 2048)    // W_xproj padded to 128 rows
#define S2 (2048 * 64)     // W_dt
#define S3 (1024 * 2048)   // W_out
#define S4 (BL * DBL_LD)   // dbl zero-init (for split-K atomics)

__global__ __launch_bounds__(256) void wcvt_kernel(
    const float* __restrict__ Win, const float* __restrict__ Wx,
    const float* __restrict__ Wdt, const float* __restrict__ Wout,
    bf16* __restrict__ win_bf, bf16* __restrict__ wx_bf,
    bf16* __restrict__ wdt_bf, bf16* __restrict__ wout_bf,
    float* __restrict__ dbl)
{
    int id = blockIdx.x * 256 + threadIdx.x;
    if (id < S0) { win_bf[id] = f2b(Win[id]); return; }
    id -= S0;
    if (id < S1) { wx_bf[id] = (id < 96 * 2048) ? f2b(Wx[id]) : f2b(0.f); return; }
    id -= S1;
    if (id < S2) { wdt_bf[id] = f2b(Wdt[id]); return; }
    id -= S2;
    if (id < S3) { wout_bf[id] = f2b(Wout[id]); return; }
    id -= S3;
    dbl[id] = 0.f;
}

// ============ bf16 MFMA GEMM (R9-proven, BK=32): C = A[M,K] * B[N,K]^T =======
// epi: 1=+bias softplus (fp32 C); 2=+resid (fp32 C); 3=atomicAdd (split-K);
//      4=bf16 store to C2; 5=+bias softplus bf16 store to C2
#define GTM 128
#define GTN 128
#define GTK 32

__global__ __launch_bounds__(256) void gemm_bf(
    const bf16* __restrict__ A, int lda,
    const bf16* __restrict__ B, int ldb,
    float* __restrict__ C, int ldc,
    int N, int K, int epi,
    const float* __restrict__ bias,
    const float* __restrict__ resid,
    bf16* __restrict__ C2)
{
    __shared__ short As[GTM * GTK];   // 8 KB
    __shared__ short Bs[GTN * GTK];   // 8 KB
    const int tid  = threadIdx.x;
    const int lane = tid & 63;
    const int wave = tid >> 6;            // 0..3
    const int wm = (wave & 1) * 64;
    const int wn = (wave >> 1) * 64;
    const int bm = blockIdx.y * GTM;
    const int bn = blockIdx.x * GTN;
    const int kbase = blockIdx.z * K;     // split-K base (K = slice length)

    floatx4 acc[4][4];
#pragma unroll
    for (int i = 0; i < 4; ++i)
#pragma unroll
        for (int j = 0; j < 4; ++j) acc[i][j] = (floatx4){0.f, 0.f, 0.f, 0.f};

    const int srow = wave * 16 + (lane >> 2);   // 0..63 (per pass)
    const int scol = (lane & 3) * 8;            // bf16 col within k-tile
    const int fm = lane & 15;
    const int q  = lane >> 4;

    for (int k0 = 0; k0 < K; k0 += GTK) {
#pragma unroll
        for (int r = 0; r < 2; ++r) {
            const int m = r * 64 + srow;
            gload16(A + (size_t)(bm + m) * lda + kbase + k0 + scol,
                    As + m * GTK + scol);
            gload16(B + (size_t)(bn + m) * ldb + kbase + k0 + scol,
                    Bs + m * GTK + scol);
        }
        __syncthreads();

        short8 af[4], bfr[4];
#pragma unroll
        for (int i = 0; i < 4; ++i)
            af[i] = *(short8*)&As[(wm + i * 16 + fm) * GTK + q * 8];
#pragma unroll
        for (int j = 0; j < 4; ++j)
            bfr[j] = *(short8*)&Bs[(wn + j * 16 + fm) * GTK + q * 8];
#pragma unroll
        for (int i = 0; i < 4; ++i)
#pragma unroll
            for (int j = 0; j < 4; ++j)
                acc[i][j] = __builtin_amdgcn_mfma_f32_16x16x32_bf16(
                    af[i], bfr[j], acc[i][j], 0, 0, 0);
        __syncthreads();
    }

    // C/D layout: col=lane&15, row=(lane>>4)*4+reg  [m89/m91-verified]
    const int col = lane & 15;
    const int rq  = (lane >> 4) * 4;
#pragma unroll
    for (int i = 0; i < 4; ++i) {
#pragma unroll
        for (int j = 0; j < 4; ++j) {
#pragma unroll
            for (int r = 0; r < 4; ++r) {
                const int gm = bm + wm + i * 16 + rq + r;
                const int gn = bn + wn + j * 16 + col;
                if (gn >= N) continue;
                float v = acc[i][j][r];
                if (epi == 1) {
                    C[(size_t)gm * ldc + gn] = fsoftp(v + bias[gn]);
                } else if (epi == 2) {
                    C[(size_t)gm * ldc + gn] = v + resid[(size_t)gm * ldc + gn];
                } else if (epi == 3) {
                    atomicAdd(&C[(size_t)gm * ldc + gn], v);
                } else if (epi == 4) {
                    C2[(size_t)gm * ldc + gn] = f2b(v);
                } else {  // 5
                    C2[(size_t)gm * ldc + gn] = f2b(fsoftp(v + bias[gn]));
                }
            }
        }
    }
}

// ------------- conv(4)+SiLU: reads bf16 xz u-half, writes bf16 uc -----------
__global__ __launch_bounds__(256) void conv_par3(
    const bf16* __restrict__ xzbf, const float* __restrict__ cw,
    const float* __restrict__ cb, bf16* __restrict__ ucb)
{
    const int id = blockIdx.x * 256 + threadIdx.x;  // = (b*LL+t)*D_INNER+d
    const int d = id & (D_INNER - 1);
    const int t = (id >> 11) & (LL - 1);
    const int b = id >> 22;
    float acc = cb[d];
#pragma unroll
    for (int k = 0; k < 4; ++k) {
        const int tt = t - 3 + k;
        if (tt >= 0)
            acc += (float)xzbf[(size_t)(b * LL + tt) * XZ_LD + d] * cw[d * 4 + k];
    }
    ucb[id] = f2b(acc * fsig(acc));
}

// ------------- dbl[:, :64] -> bf16 dt_r copy for GEMM-5 ----------------------
__global__ __launch_bounds__(256) void cvt_dtr(
    const float* __restrict__ dbl, bf16* __restrict__ dtr_bf)
{
    const int id = blockIdx.x * 256 + threadIdx.x;  // m*64+r
    const int m = id >> 6, r = id & 63;
    dtr_bf[id] = f2b(dbl[(size_t)m * DBL_LD + r]);
}

// ------------------------------ 3-phase scan ---------------------------------
// block decode: blk = ((b*NCH)+c)*8 + dgrp ; d = dgrp*256 + tid
__global__ __launch_bounds__(256) void scan_p1(
    const bf16* __restrict__ uc, const bf16* __restrict__ dtb,
    const float* __restrict__ dbl, const float* __restrict__ A_log,
    float* __restrict__ Psum, float* __restrict__ Hloc)
{
    const int blk = blockIdx.x;
    const int d = (blk & 7) * 256 + threadIdx.x;
    const int c = (blk >> 3) & (NCH - 1);
    const int b = blk >> 9;                  // NCH=64 -> 9 bits below b
    float A[D_STATE], h[D_STATE];
#pragma unroll
    for (int n = 0; n < D_STATE; ++n) {
        A[n] = -__expf(A_log[d * D_STATE + n]);
        h[n] = 0.f;
    }
    const size_t row0 = (size_t)b * LL + c * TCH;
    const bf16* dtp = dtb + row0 * D_INNER + d;
    const bf16* up  = uc  + row0 * D_INNER + d;
    const float* Bp = dbl + row0 * DBL_LD + DT_RANK;
    float S = 0.f;
    for (int t = 0; t < TCH; ++t) {
        const float dtv = (float)dtp[(size_t)t * D_INNER];
        const float uv  = (float)up[(size_t)t * D_INNER];
        const float du  = dtv * uv;
        S += dtv;
#pragma unroll
        for (int n = 0; n < D_STATE; ++n)
            h[n] = __expf(dtv * A[n]) * h[n] + du * Bp[(size_t)t * DBL_LD + n];
    }
    const size_t o = (((size_t)b * NCH + c) * D_INNER + d) * D_STATE;
#pragma unroll
    for (int n = 0; n < D_STATE; ++n) {
        Psum[o + n] = __expf(S * A[n]);
        Hloc[o + n] = h[n];
    }
}

__global__ __launch_bounds__(256) void scan_p2(
    float* __restrict__ Psum, const float* __restrict__ Hloc)
{
    const int id = blockIdx.x * 256 + threadIdx.x;
    const int dn = id & (D_INNER * D_STATE - 1);
    const int b  = id >> 15;
    float h = 0.f;
    for (int c = 0; c < NCH; ++c) {
        const size_t o = ((size_t)(b * NCH + c) * D_INNER * D_STATE) + dn;
        const float P  = Psum[o];
        const float hl = Hloc[o];
        Psum[o] = h;          // Hin for chunk c
        h = P * h + hl;
    }
}

// phase 3: replay; reads bf16 u (ucy), bf16 dt, z from bf16 xz; y overwrites ucy
__global__ __launch_bounds__(256) void scan_p3b(
    bf16* __restrict__ ucy, const bf16* __restrict__ dtb,
    const float* __restrict__ dbl, const float* __restrict__ A_log,
    const float* __restrict__ Dw, const float* __restrict__ Hin,
    const bf16* __restrict__ xzbf)
{
    const int blk = blockIdx.x;
    const int d = (blk & 7) * 256 + threadIdx.x;
    const int c = (blk >> 3) & (NCH - 1);
    const int b = blk >> 9;                  // NCH=64 -> 9 bits below b
    float A[D_STATE], h[D_STATE];
    const size_t o = (((size_t)b * NCH + c) * D_INNER + d) * D_STATE;
#pragma unroll
    for (int n = 0; n < D_STATE; ++n) {
        A[n] = -__expf(A_log[d * D_STATE + n]);
        h[n] = Hin[o + n];
    }
    const float Dd = Dw[d];
    const size_t row0 = (size_t)b * LL + c * TCH;
    const bf16* dtp = dtb + row0 * D_INNER + d;
    bf16*       uyp = ucy + row0 * D_INNER + d;     // u in, y out (same slot)
    const float* BCp = dbl + row0 * DBL_LD;
    const bf16* zp   = xzbf + row0 * XZ_LD + D_INNER + d;
    for (int t = 0; t < TCH; ++t) {
        const float dtv = (float)dtp[(size_t)t * D_INNER];
        const float uv  = (float)uyp[(size_t)t * D_INNER];
        const float du  = dtv * uv;
        float acc = uv * Dd;
        const float* Brow = BCp + (size_t)t * DBL_LD + DT_RANK;
        const float* Crow = Brow + D_STATE;
#pragma unroll
        for (int n = 0; n < D_STATE; ++n) {
            h[n] = __expf(dtv * A[n]) * h[n] + du * Brow[n];
            acc += h[n] * Crow[n];
        }
        const float zv = (float)zp[(size_t)t * XZ_LD];
        uyp[(size_t)t * D_INNER] = f2b(acc * zv * fsig(zv));
    }
}

// ---------------- fallback (small ws): R4 sequential path --------------------
#define BM 128
#define BN 128
#define BK 8

__global__ __launch_bounds__(256) void gemm_bt(
    const float* __restrict__ A, int lda,
    const float* __restrict__ Bw,
    float* __restrict__ C, int ldc,
    int M, int N, int K, int epi,
    const float* __restrict__ bias,
    const float* __restrict__ resid)
{
    __shared__ float As[BK][BM + 1];
    __shared__ float Bs[BK][BN + 1];
    const int tx = threadIdx.x, ty = threadIdx.y;
    const int tid = ty * 16 + tx;
    const int bm = blockIdx.y * BM, bn = blockIdx.x * BN;
    float acc[8][8];
#pragma unroll
    for (int i = 0; i < 8; ++i)
#pragma unroll
        for (int j = 0; j < 8; ++j) acc[i][j] = 0.f;
    for (int k0 = 0; k0 < K; k0 += BK) {
#pragma unroll
        for (int i = tid; i < BM * BK; i += 256) {
            const int m = i / BK, kk = i % BK;
            As[kk][m] = A[(size_t)(bm + m) * lda + (k0 + kk)];
        }
#pragma unroll
        for (int i = tid; i < BN * BK; i += 256) {
            const int n = i / BK, kk = i % BK;
            const int gn = bn + n;
            Bs[kk][n] = (gn < N) ? Bw[(size_t)gn * K + (k0 + kk)] : 0.f;
        }
        __syncthreads();
#pragma unroll
        for (int kk = 0; kk < BK; ++kk) {
            float av[8], bv[8];
#pragma unroll
            for (int i = 0; i < 8; ++i) av[i] = As[kk][ty * 8 + i];
#pragma unroll
            for (int j = 0; j < 8; ++j) bv[j] = Bs[kk][tx * 8 + j];
#pragma unroll
            for (int i = 0; i < 8; ++i)
#pragma unroll
                for (int j = 0; j < 8; ++j) acc[i][j] += av[i] * bv[j];
        }
        __syncthreads();
    }
#pragma unroll
    for (int i = 0; i < 8; ++i) {
        const int gm = bm + ty * 8 + i;
#pragma unroll
        for (int j = 0; j < 8; ++j) {
            const int gn = bn + tx * 8 + j;
            if (gn >= N) continue;
            float v = acc[i][j];
            if (epi == 1) {
                v += bias[gn];
                v = fmaxf(v, 0.f) + log1pf(expf(-fabsf(v)));
            } else if (epi == 2) {
                v += resid[(size_t)gm * ldc + gn];
            }
            C[(size_t)gm * ldc + gn] = v;
        }
    }
}

__global__ __launch_bounds__(256) void conv_silu_kernel(
    float* __restrict__ xz, const float* __restrict__ cw,
    const float* __restrict__ cb)
{
    const int idx = blockIdx.x * 256 + threadIdx.x;
    const int b = idx >> 11, d = idx & (D_INNER - 1);
    const float w0 = cw[d * 4 + 0], w1 = cw[d * 4 + 1];
    const float w2 = cw[d * 4 + 2], w3 = cw[d * 4 + 3];
    const float bias = cb[d];
    float* u = xz + (size_t)b * LL * XZ_LD + d;
    float x0 = 0.f, x1 = 0.f, x2 = 0.f;
    for (int t = 0; t < LL; ++t) {
        const float x3 = u[(size_t)t * XZ_LD];
        const float c = bias + x0 * w0 + x1 * w1 + x2 * w2 + x3 * w3;
        u[(size_t)t * XZ_LD] = c / (1.f + expf(-c));
        x0 = x1; x1 = x2; x2 = x3;
    }
}

__global__ __launch_bounds__(256) void scan_kernel(
    float* __restrict__ xz, const float* __restrict__ dtb,
    const float* __restrict__ dbl,
    const float* __restrict__ A_log, const float* __restrict__ Dw)
{
    const int idx = blockIdx.x * 256 + threadIdx.x;
    const int b = idx >> 11, d = idx & (D_INNER - 1);
    float A[D_STATE], h[D_STATE];
#pragma unroll
    for (int n = 0; n < D_STATE; ++n) {
        A[n] = -expf(A_log[d * D_STATE + n]);
        h[n] = 0.f;
    }
    const float Dd = Dw[d];
    const float* dtp  = dtb + (size_t)b * LL * D_INNER + d;
    float*       up   = xz  + (size_t)b * LL * XZ_LD + d;
    const float* dblp = dbl + (size_t)b * LL * DBL_LD;
    for (int t = 0; t < LL; ++t) {
        const float dtv = dtp[(size_t)t * D_INNER];
        const float uv  = up[(size_t)t * XZ_LD];
        const float zv  = up[(size_t)t * XZ_LD + D_INNER];
        const float* Brow = dblp + (size_t)t * DBL_LD + DT_RANK;
        const float* Crow = Brow + D_STATE;
        const float du = dtv * uv;
        float acc = uv * Dd;
#pragma unroll
        for (int n = 0; n < D_STATE; ++n) {
            const float dA = expf(dtv * A[n]);
            h[n] = dA * h[n] + du * Brow[n];
            acc += h[n] * Crow[n];
        }
        const float sz = zv / (1.f + expf(-zv));
        up[(size_t)t * XZ_LD] = acc * sz;
    }
}

extern "C" void kernel_launch(void* const* d_in, const int* in_sizes, int n_in,
                              void* d_out, int out_size, void* d_ws, size_t ws_size,
                              hipStream_t stream)
{
    const float* x       = (const float*)d_in[0];
    const float* ln_w    = (const float*)d_in[1];
    const float* ln_b    = (const float*)d_in[2];
    const float* W_in    = (const float*)d_in[3];
    const float* conv_w  = (const float*)d_in[4];
    const float* conv_b  = (const float*)d_in[5];
    const float* W_xproj = (const float*)d_in[6];
    const float* W_dt    = (const float*)d_in[7];
    const float* b_dt    = (const float*)d_in[8];
    const float* A_log   = (const float*)d_in[9];
    const float* Dw      = (const float*)d_in[10];
    const float* W_out   = (const float*)d_in[11];
    float* out = (float*)d_out;

    // R14 ws layout (float offsets). R13 BUG: wdt_bf was given 32768 floats
    // but S2=131072 bf16 = 65536 floats -> wout_bf tail overlapped dtr_bf
    // (clobbered last 32 rows of W_out -> absmax 1.19). Corrected:
    //   dtb_bf [0,        4194304)   bf16 dt [4096x2048]
    //   xzbf   [4194304, 12582912)   bf16 [u|z] [4096x4096]
    //   Psum   [12582912, 16777216)
    //   Hloc   [16777216, 20971520)
    //   dbl    [20971520, 21364736)  fp32 [4096x96]
    //   ucy    [21364736, 25559040)  bf16 conv(u), then y
    //   xn_bf  [25559040, 27656192)  bf16 [4096x1024]
    //   win_bf [27656192, 29753344)  bf16 [4096x1024]
    //   wx_bf  [29753344, 29884416)  S1/2 = 131072 f
    //   wdt_bf [29884416, 29949952)  S2/2 =  65536 f
    //   wout_bf[29949952, 30998528)  S3/2 = 1048576 f
    //   dtr_bf [30998528, 31129600)  131072 f
    // total = 31129600 f = 118.7 MiB
    float* wsf     = (float*)d_ws;
    bf16*  dtb_bf  = (bf16*)wsf;
    bf16*  xzbf    = (bf16*)(wsf + 4194304);
    float* Psum    = wsf + 12582912;
    float* Hloc    = wsf + 16777216;
    float* dbl     = wsf + 20971520;
    bf16*  ucy     = (bf16*)(wsf + 21364736);
    bf16*  xn_bf   = (bf16*)(wsf + 25559040);
    bf16*  win_bf  = (bf16*)(wsf + 27656192);
    bf16*  wx_bf   = (bf16*)(wsf + 29753344);
    bf16*  wdt_bf  = wx_bf + S1;
    bf16*  wout_bf = wdt_bf + S2;
    bf16*  dtr_bf  = (bf16*)(wsf + 30998528);
    const size_t need_big = (size_t)31129600 * sizeof(float);

    if (ws_size >= need_big) {
        // out := x FIRST (L2 hygiene — see R9 post-mortem)
        init_out<<<BL * D_MODEL / 4 / 256, 256, 0, stream>>>(x, out);
        wcvt_kernel<<<(S0 + S1 + S2 + S3 + S4) / 256, 256, 0, stream>>>(
            W_in, W_xproj, W_dt, W_out, win_bf, wx_bf, wdt_bf, wout_bf, dbl);
        ln_kernel<<<BL, 256, 0, stream>>>(x, ln_w, ln_b, nullptr, xn_bf);
        // G2: xz = xn @ W_in^T  (M=4096, N=4096, K=1024), bf16 store
        gemm_bf<<<dim3(XZ_LD / GTN, BL / GTM, 1), 256, 0, stream>>>(
            xn_bf, D_MODEL, win_bf, D_MODEL, nullptr, XZ_LD,
            XZ_LD, D_MODEL, 4, nullptr, nullptr, xzbf);
        // conv+SiLU: bf16 u -> bf16 uc
        conv_par3<<<(size_t)BL * D_INNER / 256, 256, 0, stream>>>(
            xzbf, conv_w, conv_b, ucy);
        // G4: dbl += uc @ W_xproj^T  (N=96 pad 128, split-K=8, atomic)
        gemm_bf<<<dim3(1, BL / GTM, 8), 256, 0, stream>>>(
            ucy, D_INNER, wx_bf, D_INNER, dbl, DBL_LD,
            DBL_LD, D_INNER / 8, 3, nullptr, nullptr, nullptr);
        cvt_dtr<<<BL * DT_RANK / 256, 256, 0, stream>>>(dbl, dtr_bf);
        // G5: dt = softplus(dt_r @ W_dt^T + b_dt), bf16 store
        gemm_bf<<<dim3(D_INNER / GTN, BL / GTM, 1), 256, 0, stream>>>(
            dtr_bf, DT_RANK, wdt_bf, DT_RANK, nullptr, D_INNER,
            D_INNER, DT_RANK, 5, b_dt, nullptr, dtb_bf);
        // chunked scan, NCH=64
        scan_p1<<<BB * NCH * 8, 256, 0, stream>>>(
            ucy, dtb_bf, dbl, A_log, Psum, Hloc);
        scan_p2<<<BB * D_INNER * D_STATE / 256, 256, 0, stream>>>(Psum, Hloc);
        scan_p3b<<<BB * NCH * 8, 256, 0, stream>>>(
            ucy, dtb_bf, dbl, A_log, Dw, Psum, xzbf);
        // G7: out += y @ W_out^T  (N=1024, split-K=2, atomic; out pre-init to x)
        gemm_bf<<<dim3(D_MODEL / GTN, BL / GTM, 2), 256, 0, stream>>>(
            ucy, D_INNER, wout_bf, D_INNER, out, D_MODEL,
            D_MODEL, D_INNER / 2, 3, nullptr, nullptr, nullptr);
    } else {
        float* fdtb = wsf;
        float* fxn  = fdtb;
        float* fxz  = fdtb + (size_t)BL * D_INNER;
        float* fdbl = fxz + (size_t)BL * XZ_LD;
        ln_kernel<<<BL, 256, 0, stream>>>(x, ln_w, ln_b, fxn, nullptr);
        dim3 blk(16, 16);
        gemm_bt<<<dim3(XZ_LD / BN, BL / BM), blk, 0, stream>>>(
            fxn, D_MODEL, W_in, fxz, XZ_LD, BL, XZ_LD, D_MODEL, 0, nullptr, nullptr);
        conv_silu_kernel<<<(BB * D_INNER) / 256, 256, 0, stream>>>(fxz, conv_w, conv_b);
        gemm_bt<<<dim3(1, BL / BM), blk, 0, stream>>>(
            fxz, XZ_LD, W_xproj, fdbl, DBL_LD, BL, DBL_LD, D_INNER, 0, nullptr, nullptr);
        gemm_bt<<<dim3(D_INNER / BN, BL / BM), blk, 0, stream>>>(
            fdbl, DBL_LD, W_dt, fdtb, D_INNER, BL, D_INNER, DT_RANK, 1, b_dt, nullptr);
        scan_kernel<<<(BB * D_INNER) / 256, 256, 0, stream>>>(fxz, fdtb, fdbl, A_log, Dw);
        gemm_bt<<<dim3(D_MODEL / BN, BL / BM), blk, 0, stream>>>(
            fxz, XZ_LD, W_out, out, D_MODEL, BL, D_MODEL, D_INNER, 2, nullptr, x);
    }
}

// Round 15
// 392.543 us; speedup vs baseline: 1.1016x; 1.0297x over previous
//
#include <hip/hip_runtime.h>
#include <hip/hip_bf16.h>
#include <stdint.h>

typedef __hip_bfloat16 bf16;
typedef __attribute__((ext_vector_type(8))) short short8;
typedef __attribute__((ext_vector_type(4))) float floatx4;

#define D_MODEL 1024
#define D_STATE 16
#define D_INNER 2048
#define DT_RANK 64
#define BB 2
#define LL 2048
#define BL (BB * LL)            // 4096 rows
#define XZ_LD (2 * D_INNER)     // 4096 (fallback path only)
#define DBL_LD (DT_RANK + 2 * D_STATE)  // 96
#define NCH 64                  // time chunks for parallel scan
#define TCH (LL / NCH)          // 32 steps per chunk

__device__ __forceinline__ bf16 f2b(float f) { return __float2bfloat16(f); }

// fast sigmoid / softplus via native v_exp/v_log/v_rcp (~3e-7 rel err)
__device__ __forceinline__ float fsig(float v)  { return __fdividef(1.f, 1.f + __expf(-v)); }
__device__ __forceinline__ float fsoftp(float v){ return fmaxf(v, 0.f) + __logf(1.f + __expf(-fabsf(v))); }

// async 16B global -> LDS (wave-uniform LDS base + lane*16; rows contiguous)
__device__ __forceinline__ void gload16(const void* g, void* l) {
    __builtin_amdgcn_global_load_lds(
        (const __attribute__((address_space(1))) uint32_t*)(uintptr_t)g,
        (__attribute__((address_space(3))) uint32_t*)(uintptr_t)l,
        16, 0, 0);
}

#define S0 (4096 * 1024)   // W_in
#define S1 (128 * 2048)    // W_xproj padded to 128 rows
#define S2 (2048 * 64)     // W_dt
#define S3 (1024 * 2048)   // W_out
#define S4 (BL * DBL_LD)   // dbl zero-init (for split-K atomics)
#define WCVT_TOT (S0 + S1 + S2 + S3 + S4)   // 7077888 -> 27648 blocks

// ---------------- fused prep: LayerNorm (blocks 0..BL-1) + weight cvt --------
__global__ __launch_bounds__(256) void prep_kernel(
    const float* __restrict__ x, const float* __restrict__ w,
    const float* __restrict__ b, bf16* __restrict__ xnb,
    const float* __restrict__ Win, const float* __restrict__ Wx,
    const float* __restrict__ Wdt, const float* __restrict__ Wout,
    bf16* __restrict__ win_bf, bf16* __restrict__ wx_bf,
    bf16* __restrict__ wdt_bf, bf16* __restrict__ wout_bf,
    float* __restrict__ dbl)
{
    __shared__ float s1[256], s2[256];
    const int tid = threadIdx.x;
    if (blockIdx.x < BL) {
        const int row = blockIdx.x;
        const float* xr = x + (size_t)row * D_MODEL;
        float v[4], sum = 0.f, sq = 0.f;
#pragma unroll
        for (int i = 0; i < 4; ++i) {
            v[i] = xr[tid + 256 * i];
            sum += v[i];
            sq  += v[i] * v[i];
        }
        s1[tid] = sum; s2[tid] = sq;
        __syncthreads();
        for (int s = 128; s > 0; s >>= 1) {
            if (tid < s) { s1[tid] += s1[tid + s]; s2[tid] += s2[tid + s]; }
            __syncthreads();
        }
        const float mu  = s1[0] * (1.f / D_MODEL);
        const float var = s2[0] * (1.f / D_MODEL) - mu * mu;
        const float rs  = rsqrtf(var + 1e-5f);
#pragma unroll
        for (int i = 0; i < 4; ++i) {
            const int c = tid + 256 * i;
            xnb[(size_t)row * D_MODEL + c] = f2b((v[i] - mu) * rs * w[c] + b[c]);
        }
    } else {
        int id = (blockIdx.x - BL) * 256 + tid;
        if (id < S0) { win_bf[id] = f2b(Win[id]); return; }
        id -= S0;
        if (id < S1) { wx_bf[id] = (id < 96 * 2048) ? f2b(Wx[id]) : f2b(0.f); return; }
        id -= S1;
        if (id < S2) { wdt_bf[id] = f2b(Wdt[id]); return; }
        id -= S2;
        if (id < S3) { wout_bf[id] = f2b(Wout[id]); return; }
        id -= S3;
        dbl[id] = 0.f;
    }
}

// ------------- final reduce: out = x + p0 + p1 (float4) ----------------------
__global__ __launch_bounds__(256) void reduce_out(
    const float* __restrict__ x, const float* __restrict__ p0,
    const float* __restrict__ p1, float* __restrict__ out)
{
    const int id = blockIdx.x * 256 + threadIdx.x;
    const float4 a = ((const float4*)x)[id];
    const float4 u = ((const float4*)p0)[id];
    const float4 v = ((const float4*)p1)[id];
    float4 r;
    r.x = a.x + u.x + v.x; r.y = a.y + u.y + v.y;
    r.z = a.z + u.z + v.z; r.w = a.w + u.w + v.w;
    ((float4*)out)[id] = r;
}

// ============ bf16 MFMA GEMM (R9-proven, BK=32): C = A[M,K] * B[N,K]^T =======
// epi: 0=plain fp32 store to slab C + blockIdx.z*BL*D_MODEL (G7 split-K slabs);
//      1=+bias softplus (fp32 C); 3=atomicAdd (split-K); 4=u/z split
//      (gn<D_INNER -> fp32 C, else bf16 C2); 5=+bias softplus bf16 to C2
#define GTM 128
#define GTN 128
#define GTK 32

__global__ __launch_bounds__(256) void gemm_bf(
    const bf16* __restrict__ A, int lda,
    const bf16* __restrict__ B, int ldb,
    float* __restrict__ C, int ldc,
    int N, int K, int epi,
    const float* __restrict__ bias,
    bf16* __restrict__ C2)
{
    __shared__ short As[GTM * GTK];   // 8 KB
    __shared__ short Bs[GTN * GTK];   // 8 KB
    const int tid  = threadIdx.x;
    const int lane = tid & 63;
    const int wave = tid >> 6;            // 0..3
    const int wm = (wave & 1) * 64;
    const int wn = (wave >> 1) * 64;
    const int bm = blockIdx.y * GTM;
    const int bn = blockIdx.x * GTN;
    const int kbase = blockIdx.z * K;     // split-K base (K = slice length)

    floatx4 acc[4][4];
#pragma unroll
    for (int i = 0; i < 4; ++i)
#pragma unroll
        for (int j = 0; j < 4; ++j) acc[i][j] = (floatx4){0.f, 0.f, 0.f, 0.f};

    const int srow = wave * 16 + (lane >> 2);   // 0..63 (per pass)
    const int scol = (lane & 3) * 8;            // bf16 col within k-tile
    const int fm = lane & 15;
    const int q  = lane >> 4;

    for (int k0 = 0; k0 < K; k0 += GTK) {
#pragma unroll
        for (int r = 0; r < 2; ++r) {
            const int m = r * 64 + srow;
            gload16(A + (size_t)(bm + m) * lda + kbase + k0 + scol,
                    As + m * GTK + scol);
            gload16(B + (size_t)(bn + m) * ldb + kbase + k0 + scol,
                    Bs + m * GTK + scol);
        }
        __syncthreads();

        short8 af[4], bfr[4];
#pragma unroll
        for (int i = 0; i < 4; ++i)
            af[i] = *(short8*)&As[(wm + i * 16 + fm) * GTK + q * 8];
#pragma unroll
        for (int j = 0; j < 4; ++j)
            bfr[j] = *(short8*)&Bs[(wn + j * 16 + fm) * GTK + q * 8];
#pragma unroll
        for (int i = 0; i < 4; ++i)
#pragma unroll
            for (int j = 0; j < 4; ++j)
                acc[i][j] = __builtin_amdgcn_mfma_f32_16x16x32_bf16(
                    af[i], bfr[j], acc[i][j], 0, 0, 0);
        __syncthreads();
    }

    // C/D layout: col=lane&15, row=(lane>>4)*4+reg  [m89/m91-verified]
    const int col = lane & 15;
    const int rq  = (lane >> 4) * 4;
#pragma unroll
    for (int i = 0; i < 4; ++i) {
#pragma unroll
        for (int j = 0; j < 4; ++j) {
#pragma unroll
            for (int r = 0; r < 4; ++r) {
                const int gm = bm + wm + i * 16 + rq + r;
                const int gn = bn + wn + j * 16 + col;
                if (gn >= N) continue;
                float v = acc[i][j][r];
                if (epi == 0) {
                    C[(size_t)blockIdx.z * BL * D_MODEL +
                      (size_t)gm * ldc + gn] = v;
                } else if (epi == 1) {
                    C[(size_t)gm * ldc + gn] = fsoftp(v + bias[gn]);
                } else if (epi == 3) {
                    atomicAdd(&C[(size_t)gm * ldc + gn], v);
                } else if (epi == 4) {
                    if (gn < D_INNER) C[(size_t)gm * ldc + gn] = v;
                    else C2[(size_t)gm * (size_t)D_INNER + (gn - D_INNER)] = f2b(v);
                } else {  // 5
                    C2[(size_t)gm * ldc + gn] = f2b(fsoftp(v + bias[gn]));
                }
            }
        }
    }
}

// ------------- conv(4)+SiLU: reads fp32 uraw, writes bf16 uc -----------------
__global__ __launch_bounds__(256) void conv_par3(
    const float* __restrict__ uraw, const float* __restrict__ cw,
    const float* __restrict__ cb, bf16* __restrict__ ucb)
{
    const int id = blockIdx.x * 256 + threadIdx.x;  // = (b*LL+t)*D_INNER+d
    const int d = id & (D_INNER - 1);
    const int t = (id >> 11) & (LL - 1);
    float acc = cb[d];
#pragma unroll
    for (int k = 0; k < 4; ++k) {
        const int tt = t - 3 + k;
        if (tt >= 0)
            acc += uraw[(size_t)id + (size_t)(k - 3) * D_INNER] * cw[d * 4 + k];
    }
    ucb[id] = f2b(acc * fsig(acc));
}

// ------------- dbl[:, :64] -> bf16 dt_r copy for GEMM-5 ----------------------
__global__ __launch_bounds__(256) void cvt_dtr(
    const float* __restrict__ dbl, bf16* __restrict__ dtr_bf)
{
    const int id = blockIdx.x * 256 + threadIdx.x;  // m*64+r
    const int m = id >> 6, r = id & 63;
    dtr_bf[id] = f2b(dbl[(size_t)m * DBL_LD + r]);
}

// ------------------------------ 3-phase scan ---------------------------------
// block decode: blk = ((b*NCH)+c)*8 + dgrp ; d = dgrp*256 + tid
__global__ __launch_bounds__(256) void scan_p1(
    const bf16* __restrict__ uc, const bf16* __restrict__ dtb,
    const float* __restrict__ dbl, const float* __restrict__ A_log,
    float* __restrict__ Psum, float* __restrict__ Hloc)
{
    const int blk = blockIdx.x;
    const int d = (blk & 7) * 256 + threadIdx.x;
    const int c = (blk >> 3) & (NCH - 1);
    const int b = blk >> 9;                  // NCH=64 -> 9 bits below b
    float A[D_STATE], h[D_STATE];
#pragma unroll
    for (int n = 0; n < D_STATE; ++n) {
        A[n] = -__expf(A_log[d * D_STATE + n]);
        h[n] = 0.f;
    }
    const size_t row0 = (size_t)b * LL + c * TCH;
    const bf16* dtp = dtb + row0 * D_INNER + d;
    const bf16* up  = uc  + row0 * D_INNER + d;
    const float* Bp = dbl + row0 * DBL_LD + DT_RANK;
    float S = 0.f;
    for (int t = 0; t < TCH; ++t) {
        const float dtv = (float)dtp[(size_t)t * D_INNER];
        const float uv  = (float)up[(size_t)t * D_INNER];
        const float du  = dtv * uv;
        S += dtv;
#pragma unroll
        for (int n = 0; n < D_STATE; ++n)
            h[n] = __expf(dtv * A[n]) * h[n] + du * Bp[(size_t)t * DBL_LD + n];
    }
    const size_t o = (((size_t)b * NCH + c) * D_INNER + d) * D_STATE;
#pragma unroll
    for (int n = 0; n < D_STATE; ++n) {
        Psum[o + n] = __expf(S * A[n]);
        Hloc[o + n] = h[n];
    }
}

__global__ __launch_bounds__(256) void scan_p2(
    float* __restrict__ Psum, const float* __restrict__ Hloc)
{
    const int id = blockIdx.x * 256 + threadIdx.x;
    const int dn = id & (D_INNER * D_STATE - 1);
    const int b  = id >> 15;
    float h = 0.f;
    for (int c = 0; c < NCH; ++c) {
        const size_t o = ((size_t)(b * NCH + c) * D_INNER * D_STATE) + dn;
        const float P  = Psum[o];
        const float hl = Hloc[o];
        Psum[o] = h;          // Hin for chunk c
        h = P * h + hl;
    }
}

// phase 3: replay; bf16 u (ucy), bf16 dt, bf16 z (zbf); y overwrites ucy
__global__ __launch_bounds__(256) void scan_p3b(
    bf16* __restrict__ ucy, const bf16* __restrict__ dtb,
    const float* __restrict__ dbl, const float* __restrict__ A_log,
    const float* __restrict__ Dw, const float* __restrict__ Hin,
    const bf16* __restrict__ zbf)
{
    const int blk = blockIdx.x;
    const int d = (blk & 7) * 256 + threadIdx.x;
    const int c = (blk >> 3) & (NCH - 1);
    const int b = blk >> 9;                  // NCH=64 -> 9 bits below b
    float A[D_STATE], h[D_STATE];
    const size_t o = (((size_t)b * NCH + c) * D_INNER + d) * D_STATE;
#pragma unroll
    for (int n = 0; n < D_STATE; ++n) {
        A[n] = -__expf(A_log[d * D_STATE + n]);
        h[n] = Hin[o + n];
    }
    const float Dd = Dw[d];
    const size_t row0 = (size_t)b * LL + c * TCH;
    const bf16* dtp = dtb + row0 * D_INNER + d;
    bf16*       uyp = ucy + row0 * D_INNER + d;     // u in, y out (same slot)
    const float* BCp = dbl + row0 * DBL_LD;
    const bf16* zp   = zbf + row0 * D_INNER + d;
    for (int t = 0; t < TCH; ++t) {
        const float dtv = (float)dtp[(size_t)t * D_INNER];
        const float uv  = (float)uyp[(size_t)t * D_INNER];
        const float du  = dtv * uv;
        float acc = uv * Dd;
        const float* Brow = BCp + (size_t)t * DBL_LD + DT_RANK;
        const float* Crow = Brow + D_STATE;
#pragma unroll
        for (int n = 0; n < D_STATE; ++n) {
            h[n] = __expf(dtv * A[n]) * h[n] + du * Brow[n];
            acc += h[n] * Crow[n];
        }
        const float zv = (float)zp[(size_t)t * D_INNER];
        uyp[(size_t)t * D_INNER] = f2b(acc * zv * fsig(zv));
    }
}

// ---------------- fallback (small ws): R4 sequential path --------------------
#define BM 128
#define BN 128
#define BK 8

__global__ __launch_bounds__(256) void ln_kernel(
    const float* __restrict__ x, const float* __restrict__ w,
    const float* __restrict__ b, float* __restrict__ xnf)
{
    __shared__ float s1[256], s2[256];
    const int row = blockIdx.x;
    const int tid = threadIdx.x;
    const float* xr = x + (size_t)row * D_MODEL;
    float v[4], sum = 0.f, sq = 0.f;
#pragma unroll
    for (int i = 0; i < 4; ++i) {
        v[i] = xr[tid + 256 * i];
        sum += v[i];
        sq  += v[i] * v[i];
    }
    s1[tid] = sum; s2[tid] = sq;
    __syncthreads();
    for (int s = 128; s > 0; s >>= 1) {
        if (tid < s) { s1[tid] += s1[tid + s]; s2[tid] += s2[tid + s]; }
        __syncthreads();
    }
    const float mu  = s1[0] * (1.f / D_MODEL);
    const float var = s2[0] * (1.f / D_MODEL) - mu * mu;
    const float rs  = rsqrtf(var + 1e-5f);
#pragma unroll
    for (int i = 0; i < 4; ++i) {
        const int c = tid + 256 * i;
        xnf[(size_t)row * D_MODEL + c] = (v[i] - mu) * rs * w[c] + b[c];
    }
}

__global__ __launch_bounds__(256) void gemm_bt(
    const float* __restrict__ A, int lda,
    const float* __restrict__ Bw,
    float* __restrict__ C, int ldc,
    int M, int N, int K, int epi,
    const float* __restrict__ bias,
    const float* __restrict__ resid)
{
    __shared__ float As[BK][BM + 1];
    __shared__ float Bs[BK][BN + 1];
    const int tx = threadIdx.x, ty = threadIdx.y;
    const int tid = ty * 16 + tx;
    const int bm = blockIdx.y * BM, bn = blockIdx.x * BN;
    float acc[8][8];
#pragma unroll
    for (int i = 0; i < 8; ++i)
#pragma unroll
        for (int j = 0; j < 8; ++j) acc[i][j] = 0.f;
    for (int k0 = 0; k0 < K; k0 += BK) {
#pragma unroll
        for (int i = tid; i < BM * BK; i += 256) {
            const int m = i / BK, kk = i % BK;
            As[kk][m] = A[(size_t)(bm + m) * lda + (k0 + kk)];
        }
#pragma unroll
        for (int i = tid; i < BN * BK; i += 256) {
            const int n = i / BK, kk = i % BK;
            const int gn = bn + n;
            Bs[kk][n] = (gn < N) ? Bw[(size_t)gn * K + (k0 + kk)] : 0.f;
        }
        __syncthreads();
#pragma unroll
        for (int kk = 0; kk < BK; ++kk) {
            float av[8], bv[8];
#pragma unroll
            for (int i = 0; i < 8; ++i) av[i] = As[kk][ty * 8 + i];
#pragma unroll
            for (int j = 0; j < 8; ++j) bv[j] = Bs[kk][tx * 8 + j];
#pragma unroll
            for (int i = 0; i < 8; ++i)
#pragma unroll
                for (int j = 0; j < 8; ++j) acc[i][j] += av[i] * bv[j];
        }
        __syncthreads();
    }
#pragma unroll
    for (int i = 0; i < 8; ++i) {
        const int gm = bm + ty * 8 + i;
#pragma unroll
        for (int j = 0; j < 8; ++j) {
            const int gn = bn + tx * 8 + j;
            if (gn >= N) continue;
            float v = acc[i][j];
            if (epi == 1) {
                v += bias[gn];
                v = fmaxf(v, 0.f) + log1pf(expf(-fabsf(v)));
            } else if (epi == 2) {
                v += resid[(size_t)gm * ldc + gn];
            }
            C[(size_t)gm * ldc + gn] = v;
        }
    }
}

__global__ __launch_bounds__(256) void conv_silu_kernel(
    float* __restrict__ xz, const float* __restrict__ cw,
    const float* __restrict__ cb)
{
    const int idx = blockIdx.x * 256 + threadIdx.x;
    const int b = idx >> 11, d = idx & (D_INNER - 1);
    const float w0 = cw[d * 4 + 0], w1 = cw[d * 4 + 1];
    const float w2 = cw[d * 4 + 2], w3 = cw[d * 4 + 3];
    const float bias = cb[d];
    float* u = xz + (size_t)b * LL * XZ_LD + d;
    float x0 = 0.f, x1 = 0.f, x2 = 0.f;
    for (int t = 0; t < LL; ++t) {
        const float x3 = u[(size_t)t * XZ_LD];
        const float c = bias + x0 * w0 + x1 * w1 + x2 * w2 + x3 * w3;
        u[(size_t)t * XZ_LD] = c / (1.f + expf(-c));
        x0 = x1; x1 = x2; x2 = x3;
    }
}

__global__ __launch_bounds__(256) void scan_kernel(
    float* __restrict__ xz, const float* __restrict__ dtb,
    const float* __restrict__ dbl,
    const float* __restrict__ A_log, const float* __restrict__ Dw)
{
    const int idx = blockIdx.x * 256 + threadIdx.x;
    const int b = idx >> 11, d = idx & (D_INNER - 1);
    float A[D_STATE], h[D_STATE];
#pragma unroll
    for (int n = 0; n < D_STATE; ++n) {
        A[n] = -expf(A_log[d * D_STATE + n]);
        h[n] = 0.f;
    }
    const float Dd = Dw[d];
    const float* dtp  = dtb + (size_t)b * LL * D_INNER + d;
    float*       up   = xz  + (size_t)b * LL * XZ_LD + d;
    const float* dblp = dbl + (size_t)b * LL * DBL_LD;
    for (int t = 0; t < LL; ++t) {
        const float dtv = dtp[(size_t)t * D_INNER];
        const float uv  = up[(size_t)t * XZ_LD];
        const float zv  = up[(size_t)t * XZ_LD + D_INNER];
        const float* Brow = dblp + (size_t)t * DBL_LD + DT_RANK;
        const float* Crow = Brow + D_STATE;
        const float du = dtv * uv;
        float acc = uv * Dd;
#pragma unroll
        for (int n = 0; n < D_STATE; ++n) {
            const float dA = expf(dtv * A[n]);
            h[n] = dA * h[n] + du * Brow[n];
            acc += h[n] * Crow[n];
        }
        const float sz = zv / (1.f + expf(-zv));
        up[(size_t)t * XZ_LD] = acc * sz;
    }
}

extern "C" void kernel_launch(void* const* d_in, const int* in_sizes, int n_in,
                              void* d_out, int out_size, void* d_ws, size_t ws_size,
                              hipStream_t stream)
{
    const float* x       = (const float*)d_in[0];
    const float* ln_w    = (const float*)d_in[1];
    const float* ln_b    = (const float*)d_in[2];
    const float* W_in    = (const float*)d_in[3];
    const float* conv_w  = (const float*)d_in[4];
    const float* conv_b  = (const float*)d_in[5];
    const float* W_xproj = (const float*)d_in[6];
    const float* W_dt    = (const float*)d_in[7];
    const float* b_dt    = (const float*)d_in[8];
    const float* A_log   = (const float*)d_in[9];
    const float* Dw      = (const float*)d_in[10];
    const float* W_out   = (const float*)d_in[11];
    float* out = (float*)d_out;

    // R15 ws layout (float offsets), 134.8 MiB (each size re-audited):
    //   dtb_bf [0,        4194304)   bf16 dt 4096x2048      (4194304 f)
    //   uraw   [4194304, 12582912)   fp32 u  4096x2048      (8388608 f)
    //   zbf    [12582912, 16777216)  bf16 z  4096x2048      (4194304 f)
    //   Psum   [16777216, 20971520)  fp32; later G7 slab 0  (4194304 f)
    //   Hloc   [20971520, 25165824)  fp32; later G7 slab 1  (4194304 f)
    //   dbl    [25165824, 25559040)  fp32 4096x96           (393216 f)
    //   ucy    [25559040, 29753344)  bf16 conv(u) then y    (4194304 f)
    //   xn_bf  [29753344, 31850496)  bf16 4096x1024         (2097152 f)
    //   win_bf [31850496, 33947648)  bf16 4096x1024         (2097152 f)
    //   wx_bf  [33947648, 34078720)  S1/2 = 131072 f
    //   wdt_bf [34078720, 34144256)  S2/2 =  65536 f
    //   wout_bf[34144256, 35192832)  S3/2 = 1048576 f
    //   dtr_bf [35192832, 35323904)  131072 f
    float* wsf     = (float*)d_ws;
    bf16*  dtb_bf  = (bf16*)wsf;
    float* uraw    = wsf + 4194304;
    bf16*  zbf     = (bf16*)(wsf + 12582912);
    float* Psum    = wsf + 16777216;       // G7 slabs are contiguous here
    float* Hloc    = wsf + 20971520;
    float* dbl     = wsf + 25165824;
    bf16*  ucy     = (bf16*)(wsf + 25559040);
    bf16*  xn_bf   = (bf16*)(wsf + 29753344);
    bf16*  win_bf  = (bf16*)(wsf + 31850496);
    bf16*  wx_bf   = (bf16*)(wsf + 33947648);
    bf16*  wdt_bf  = (bf16*)(wsf + 34078720);
    bf16*  wout_bf = (bf16*)(wsf + 34144256);
    bf16*  dtr_bf  = (bf16*)(wsf + 35192832);
    const size_t need_big = (size_t)35323904 * sizeof(float);

    if (ws_size >= need_big) {
        // fused LN + weight cvt (+dbl zero)
        prep_kernel<<<BL + WCVT_TOT / 256, 256, 0, stream>>>(
            x, ln_w, ln_b, xn_bf,
            W_in, W_xproj, W_dt, W_out, win_bf, wx_bf, wdt_bf, wout_bf, dbl);
        // G2: [u|z] = xn @ W_in^T; u -> fp32 uraw, z -> bf16 zbf
        gemm_bf<<<dim3(XZ_LD / GTN, BL / GTM, 1), 256, 0, stream>>>(
            xn_bf, D_MODEL, win_bf, D_MODEL, uraw, D_INNER,
            XZ_LD, D_MODEL, 4, nullptr, zbf);
        // conv+SiLU: fp32 u -> bf16 uc
        conv_par3<<<(size_t)BL * D_INNER / 256, 256, 0, stream>>>(
            uraw, conv_w, conv_b, ucy);
        // G4: dbl += uc @ W_xproj^T  (N=96 pad 128, split-K=8, atomic)
        gemm_bf<<<dim3(1, BL / GTM, 8), 256, 0, stream>>>(
            ucy, D_INNER, wx_bf, D_INNER, dbl, DBL_LD,
            DBL_LD, D_INNER / 8, 3, nullptr, nullptr);
        cvt_dtr<<<BL * DT_RANK / 256, 256, 0, stream>>>(dbl, dtr_bf);
        // G5: dt = softplus(dt_r @ W_dt^T + b_dt), bf16 store
        gemm_bf<<<dim3(D_INNER / GTN, BL / GTM, 1), 256, 0, stream>>>(
            dtr_bf, DT_RANK, wdt_bf, DT_RANK, nullptr, D_INNER,
            D_INNER, DT_RANK, 5, b_dt, dtb_bf);
        // chunked scan, NCH=64
        scan_p1<<<BB * NCH * 8, 256, 0, stream>>>(
            ucy, dtb_bf, dbl, A_log, Psum, Hloc);
        scan_p2<<<BB * D_INNER * D_STATE / 256, 256, 0, stream>>>(Psum, Hloc);
        scan_p3b<<<BB * NCH * 8, 256, 0, stream>>>(
            ucy, dtb_bf, dbl, A_log, Dw, Psum, zbf);
        // G7: partials = y @ W_out^T  (split-K=2 into Psum/Hloc slabs, plain
        // fp32 stores — no atomics; Psum/Hloc dead after p3b, contiguous)
        gemm_bf<<<dim3(D_MODEL / GTN, BL / GTM, 2), 256, 0, stream>>>(
            ucy, D_INNER, wout_bf, D_INNER, Psum, D_MODEL,
            D_MODEL, D_INNER / 2, 0, nullptr, nullptr);
        // out = x + p0 + p1
        reduce_out<<<BL * D_MODEL / 4 / 256, 256, 0, stream>>>(
            x, Psum, Hloc, out);
    } else {
        float* fdtb = wsf;
        float* fxn  = fdtb;
        float* fxz  = fdtb + (size_t)BL * D_INNER;
        float* fdbl = fxz + (size_t)BL * XZ_LD;
        ln_kernel<<<BL, 256, 0, stream>>>(x, ln_w, ln_b, fxn);
        dim3 blk(16, 16);
        gemm_bt<<<dim3(XZ_LD / BN, BL / BM), blk, 0, stream>>>(
            fxn, D_MODEL, W_in, fxz, XZ_LD, BL, XZ_LD, D_MODEL, 0, nullptr, nullptr);
        conv_silu_kernel<<<(BB * D_INNER) / 256, 256, 0, stream>>>(fxz, conv_w, conv_b);
        gemm_bt<<<dim3(1, BL / BM), blk, 0, stream>>>(
            fxz, XZ_LD, W_xproj, fdbl, DBL_LD, BL, DBL_LD, D_INNER, 0, nullptr, nullptr);
        gemm_bt<<<dim3(D_INNER / BN, BL / BM), blk, 0, stream>>>(
            fdbl, DBL_LD, W_dt, fdtb, D_INNER, BL, D_INNER, DT_RANK, 1, b_dt, nullptr);
        scan_kernel<<<(BB * D_INNER) / 256, 256, 0, stream>>>(fxz, fdtb, fdbl, A_log, Dw);
        gemm_bt<<<dim3(D_MODEL / BN, BL / BM), blk, 0, stream>>>(
            fxz, XZ_LD, W_out, out, D_MODEL, BL, D_MODEL, D_INNER, 2, nullptr, x);
    }
}